// Round 1
// baseline (4713.437 us; speedup 1.0000x reference)
//
#include <hip/hip_runtime.h>

#define N_NODES 50000
#define N_EDGES 800000
#define FEA 128
#define NL 3
#define AH 512
#define NG 64

// ---------------- degree / dinv ----------------
__global__ void k_deg(const int* __restrict__ dst, float* __restrict__ deg) {
    int i = blockIdx.x * blockDim.x + threadIdx.x;
    if (i < N_EDGES) unsafeAtomicAdd(&deg[dst[i]], 1.0f);
}

__global__ void k_dinv(float* __restrict__ deg) {
    int i = blockIdx.x * blockDim.x + threadIdx.x;
    if (i < N_NODES) deg[i] = rsqrtf(deg[i] + 1.0f);
}

// ---------------- GEMM: H = X @ W  (X [N,128], W [128,128]) ----------------
// W fully staged in LDS (64 KiB). Block=256 threads. 8 rows per tile iter.
// Thread layout: c4 = tid&31 (float4 col group), rl = tid>>5 (row in tile).
__global__ __launch_bounds__(256) void k_gemm(const float* __restrict__ X,
                                              const float* __restrict__ W,
                                              float* __restrict__ H, int nrows) {
    __shared__ float Wl[FEA * FEA];   // 64 KiB
    __shared__ float Xs[8 * FEA];     // 4 KiB
    for (int i = threadIdx.x; i < FEA * FEA / 4; i += 256)
        ((float4*)Wl)[i] = ((const float4*)W)[i];
    __syncthreads();

    const int c4 = threadIdx.x & 31;
    const int rl = threadIdx.x >> 5;

    for (int r0 = blockIdx.x * 8; r0 < nrows; r0 += gridDim.x * 8) {
        int nr = min(8, nrows - r0);
        __syncthreads();
        {   // stage 8 rows coalesced: 256 float4
            int rr = threadIdx.x >> 5, cc = threadIdx.x & 31;
            if (rr < nr)
                ((float4*)Xs)[threadIdx.x] =
                    ((const float4*)(X + (size_t)(r0 + rr) * FEA))[cc];
        }
        __syncthreads();
        if (rl < nr) {
            float4 acc = {0.f, 0.f, 0.f, 0.f};
            const float* xr = Xs + rl * FEA;
#pragma unroll 16
            for (int k = 0; k < FEA; ++k) {
                float xv = xr[k];
                float4 w = ((float4*)Wl)[k * 32 + c4];
                acc.x += xv * w.x; acc.y += xv * w.y;
                acc.z += xv * w.z; acc.w += xv * w.w;
            }
            ((float4*)(H + (size_t)(r0 + rl) * FEA))[c4] = acc;
        }
    }
}

// ---------------- edge scatter: X[dst] += coef * H[src] ----------------
// thread per (edge, 4 features): 32 threads per edge.
__global__ __launch_bounds__(256) void k_scatter(const int* __restrict__ src,
                                                 const int* __restrict__ dst,
                                                 const float* __restrict__ dinv,
                                                 const float* __restrict__ H,
                                                 float* __restrict__ X) {
    long long idx = (long long)blockIdx.x * blockDim.x + threadIdx.x;
    if (idx >= (long long)N_EDGES * 32) return;
    int e  = (int)(idx >> 5);
    int f4 = (int)(idx & 31);
    int s = src[e], d = dst[e];
    float coef = dinv[s] * dinv[d];
    float4 h = ((const float4*)(H + (size_t)s * FEA))[f4];
    float* xp = X + (size_t)d * FEA + f4 * 4;
    unsafeAtomicAdd(xp + 0, h.x * coef);
    unsafeAtomicAdd(xp + 1, h.y * coef);
    unsafeAtomicAdd(xp + 2, h.z * coef);
    unsafeAtomicAdd(xp + 3, h.w * coef);
}

// ---------------- finish: X = relu(X + H*dinv^2 + b) ----------------
__global__ __launch_bounds__(256) void k_finish(float* __restrict__ X,
                                                const float* __restrict__ H,
                                                const float* __restrict__ dinv,
                                                const float* __restrict__ b) {
    int idx = blockIdx.x * blockDim.x + threadIdx.x;  // over N_NODES*32
    if (idx >= N_NODES * 32) return;
    int r = idx >> 5, f4 = idx & 31;
    float di = dinv[r];
    float d2 = di * di;
    float4 h  = ((const float4*)H)[(size_t)r * 32 + f4];
    float4 x  = ((const float4*)X)[(size_t)r * 32 + f4];
    float4 bb = ((const float4*)b)[f4];
    float4 o;
    o.x = fmaxf(x.x + h.x * d2 + bb.x, 0.f);
    o.y = fmaxf(x.y + h.y * d2 + bb.y, 0.f);
    o.z = fmaxf(x.z + h.z * d2 + bb.z, 0.f);
    o.w = fmaxf(x.w + h.w * d2 + bb.w, 0.f);
    ((float4*)X)[(size_t)r * 32 + f4] = o;
}

// ---------------- node head + pooled sums ----------------
// one wave (64 lanes) per node
__global__ __launch_bounds__(256) void k_node_pool(const float* __restrict__ X,
                                                   const int* __restrict__ batch,
                                                   const float* __restrict__ nw,
                                                   const float* __restrict__ nb,
                                                   float* __restrict__ out_node,
                                                   float* __restrict__ psum,
                                                   float* __restrict__ pcnt) {
    int wid  = (blockIdx.x * blockDim.x + threadIdx.x) >> 6;
    int lane = threadIdx.x & 63;
    if (wid >= N_NODES) return;
    float2 v = ((const float2*)(X + (size_t)wid * FEA))[lane];
    float2 w = ((const float2*)nw)[lane];
    float dot = v.x * w.x + v.y * w.y;
#pragma unroll
    for (int off = 32; off; off >>= 1) dot += __shfl_down(dot, off);
    int b = batch[wid];
    if (lane == 0) {
        out_node[wid] = dot + nb[0];
        unsafeAtomicAdd(&pcnt[b], 1.0f);
    }
    unsafeAtomicAdd(&psum[b * FEA + lane * 2 + 0], v.x);
    unsafeAtomicAdd(&psum[b * FEA + lane * 2 + 1], v.y);
}

// ---------------- final MLP per graph ----------------
__global__ __launch_bounds__(256) void k_mlp(const float* __restrict__ psum,
                                             const float* __restrict__ pcnt,
                                             const float* __restrict__ w1,
                                             const float* __restrict__ b1,
                                             const float* __restrict__ w2,
                                             const float* __restrict__ b2,
                                             float* __restrict__ out) {
    __shared__ float fea[FEA];
    __shared__ float h1[AH];
    int g = blockIdx.x;
    float cnt = fmaxf(pcnt[g], 1.0f);
    if (threadIdx.x < FEA)
        fea[threadIdx.x] = psum[g * FEA + threadIdx.x] / cnt;
    __syncthreads();
    for (int j = threadIdx.x; j < AH; j += 256) {
        float acc = b1[j];
#pragma unroll 8
        for (int k = 0; k < FEA; ++k) acc += fea[k] * w1[k * AH + j];
        h1[j] = fmaxf(acc, 0.f);
    }
    __syncthreads();
    if (threadIdx.x < FEA) {
        int f = threadIdx.x;
        float acc = b2[f];
#pragma unroll 8
        for (int k = 0; k < AH; ++k) acc += h1[k] * w2[k * FEA + f];
        out[g * FEA + f] = acc;
    }
}

extern "C" void kernel_launch(void* const* d_in, const int* in_sizes, int n_in,
                              void* d_out, int out_size, void* d_ws, size_t ws_size,
                              hipStream_t stream) {
    const float* x     = (const float*)d_in[0];
    const int*   ei    = (const int*)d_in[1];
    const int*   batch = (const int*)d_in[2];
    const float* convW = (const float*)d_in[3];
    const float* convb = (const float*)d_in[4];
    const float* w1    = (const float*)d_in[5];
    const float* b1    = (const float*)d_in[6];
    const float* w2    = (const float*)d_in[7];
    const float* b2    = (const float*)d_in[8];
    const float* nw    = (const float*)d_in[9];
    const float* nb    = (const float*)d_in[10];
    float* out = (float*)d_out;

    float* ws   = (float*)d_ws;
    float* dinv = ws;                       // 50000
    float* H    = ws + 50048;               // 6.4M
    float* X    = H + (size_t)N_NODES*FEA;  // 6.4M
    float* psum = X + (size_t)N_NODES*FEA;  // 8192
    float* pcnt = psum + NG * FEA;          // 64

    const int* src = ei;
    const int* dst = ei + N_EDGES;

    hipMemsetAsync(dinv, 0, N_NODES * sizeof(float), stream);
    k_deg<<<(N_EDGES + 255) / 256, 256, 0, stream>>>(dst, dinv);
    k_dinv<<<(N_NODES + 255) / 256, 256, 0, stream>>>(dinv);

    const float* xcur = x;
    for (int l = 0; l < NL; ++l) {
        k_gemm<<<512, 256, 0, stream>>>(xcur, convW + (size_t)l * FEA * FEA, H, N_NODES);
        hipMemsetAsync(X, 0, (size_t)N_NODES * FEA * sizeof(float), stream);
        long long sthreads = (long long)N_EDGES * 32;
        k_scatter<<<(int)((sthreads + 255) / 256), 256, 0, stream>>>(src, dst, dinv, H, X);
        k_finish<<<(N_NODES * 32 + 255) / 256, 256, 0, stream>>>(X, H, dinv, convb + (size_t)l * FEA);
        xcur = X;
    }

    hipMemsetAsync(psum, 0, (NG * FEA + NG) * sizeof(float), stream);
    k_node_pool<<<(N_NODES * 64 + 255) / 256, 256, 0, stream>>>(X, batch, nw, nb, out, psum, pcnt);
    k_mlp<<<NG, 256, 0, stream>>>(psum, pcnt, w1, b1, w2, b2, out + N_NODES);
}

// Round 2
// 893.786 us; speedup vs baseline: 5.2736x; 5.2736x over previous
//
#include <hip/hip_runtime.h>

#define N_NODES 50000
#define N_EDGES 800000
#define FEA 128
#define NL 3
#define AH 512
#define NG 64
#define NBLK 196   // ceil(50000/256)

// ---------------- degree histogram (int) ----------------
__global__ void k_deg(const int* __restrict__ dst, int* __restrict__ deg) {
    int i = blockIdx.x * blockDim.x + threadIdx.x;
    if (i < N_EDGES) atomicAdd(&deg[dst[i]], 1);
}

__global__ void k_dinv(const int* __restrict__ deg, float* __restrict__ dinv) {
    int i = blockIdx.x * blockDim.x + threadIdx.x;
    if (i < N_NODES) dinv[i] = rsqrtf((float)deg[i] + 1.0f);
}

// ---------------- 3-kernel exclusive scan -> rowptr ----------------
__device__ __forceinline__ int block_scan_incl(int v, int* wsum) {
    int lane = threadIdx.x & 63, w = threadIdx.x >> 6;
    int s = v;
#pragma unroll
    for (int off = 1; off < 64; off <<= 1) {
        int t = __shfl_up(s, off);
        if (lane >= off) s += t;
    }
    if (lane == 63) wsum[w] = s;
    __syncthreads();
    int woff = 0;
    for (int k = 0; k < w; ++k) woff += wsum[k];
    return woff + s;  // block-wide inclusive
}

__global__ __launch_bounds__(256) void k_scan1(const int* __restrict__ deg,
                                               int* __restrict__ rowptr,
                                               int* __restrict__ bsum) {
    __shared__ int wsum[4];
    int i = blockIdx.x * 256 + threadIdx.x;
    int v = (i < N_NODES) ? deg[i] : 0;
    int incl = block_scan_incl(v, wsum);
    if (i < N_NODES) rowptr[i] = incl - v;  // local exclusive
    if (threadIdx.x == 255) bsum[blockIdx.x] = incl;
}

__global__ __launch_bounds__(256) void k_scan2(int* __restrict__ bsum,
                                               int* __restrict__ boff) {
    __shared__ int wsum[4];
    int v = (threadIdx.x < NBLK) ? bsum[threadIdx.x] : 0;
    int incl = block_scan_incl(v, wsum);
    if (threadIdx.x < NBLK) boff[threadIdx.x] = incl - v;
}

__global__ __launch_bounds__(256) void k_scan3(int* __restrict__ rowptr,
                                               const int* __restrict__ boff,
                                               int* __restrict__ cursor) {
    int i = blockIdx.x * 256 + threadIdx.x;
    if (i < N_NODES) {
        int r = rowptr[i] + boff[blockIdx.x];
        rowptr[i] = r;
        cursor[i] = r;
    }
    if (i == 0) rowptr[N_NODES] = N_EDGES;
}

// ---------------- CSR fill ----------------
__global__ void k_fill(const int* __restrict__ src, const int* __restrict__ dst,
                       int* __restrict__ cursor, int* __restrict__ eidx) {
    int e = blockIdx.x * blockDim.x + threadIdx.x;
    if (e < N_EDGES) {
        int p = atomicAdd(&cursor[dst[e]], 1);
        eidx[p] = src[e];
    }
}

// ---------------- GEMM: H' = dinv * (X @ W) ----------------
__global__ __launch_bounds__(256) void k_gemm(const float* __restrict__ X,
                                              const float* __restrict__ W,
                                              const float* __restrict__ dinv,
                                              float* __restrict__ H, int nrows) {
    __shared__ float Wl[FEA * FEA];   // 64 KiB
    __shared__ float Xs[8 * FEA];     // 4 KiB
    for (int i = threadIdx.x; i < FEA * FEA / 4; i += 256)
        ((float4*)Wl)[i] = ((const float4*)W)[i];
    __syncthreads();

    const int c4 = threadIdx.x & 31;
    const int rl = threadIdx.x >> 5;

    for (int r0 = blockIdx.x * 8; r0 < nrows; r0 += gridDim.x * 8) {
        int nr = min(8, nrows - r0);
        __syncthreads();
        {
            int rr = threadIdx.x >> 5, cc = threadIdx.x & 31;
            if (rr < nr)
                ((float4*)Xs)[threadIdx.x] =
                    ((const float4*)(X + (size_t)(r0 + rr) * FEA))[cc];
        }
        __syncthreads();
        if (rl < nr) {
            float4 acc = {0.f, 0.f, 0.f, 0.f};
            const float* xr = Xs + rl * FEA;
#pragma unroll 16
            for (int k = 0; k < FEA; ++k) {
                float xv = xr[k];
                float4 w = ((float4*)Wl)[k * 32 + c4];
                acc.x += xv * w.x; acc.y += xv * w.y;
                acc.z += xv * w.z; acc.w += xv * w.w;
            }
            float s = dinv[r0 + rl];
            acc.x *= s; acc.y *= s; acc.z *= s; acc.w *= s;
            ((float4*)(H + (size_t)(r0 + rl) * FEA))[c4] = acc;
        }
    }
}

// ---------------- gather: X[d] = relu(dinv[d]*(sum H'[s] + H'[d]) + b) ----------------
// one wave per node, lane = float2 feature pair
__global__ __launch_bounds__(256) void k_gather(const int* __restrict__ rowptr,
                                                const int* __restrict__ eidx,
                                                const float* __restrict__ dinv,
                                                const float* __restrict__ H,
                                                const float* __restrict__ b,
                                                float* __restrict__ X) {
    int node = (blockIdx.x * blockDim.x + threadIdx.x) >> 6;
    int lane = threadIdx.x & 63;
    if (node >= N_NODES) return;
    int r0 = rowptr[node], r1 = rowptr[node + 1];
    float2 acc = ((const float2*)(H + (size_t)node * FEA))[lane];  // self term
    for (int base = r0; base < r1; base += 64) {
        int cnt = min(64, r1 - base);
        int my_e = (lane < cnt) ? eidx[base + lane] : 0;
        for (int j = 0; j < cnt; ++j) {
            int s = __shfl(my_e, j);
            float2 h = ((const float2*)(H + (size_t)s * FEA))[lane];
            acc.x += h.x; acc.y += h.y;
        }
    }
    float di = dinv[node];
    float2 bb = ((const float2*)b)[lane];
    float2 o;
    o.x = fmaxf(acc.x * di + bb.x, 0.f);
    o.y = fmaxf(acc.y * di + bb.y, 0.f);
    ((float2*)(X + (size_t)node * FEA))[lane] = o;
}

// ---------------- node head + pooled sums ----------------
__global__ __launch_bounds__(256) void k_node_pool(const float* __restrict__ X,
                                                   const int* __restrict__ batch,
                                                   const float* __restrict__ nw,
                                                   const float* __restrict__ nb,
                                                   float* __restrict__ out_node,
                                                   float* __restrict__ psum,
                                                   float* __restrict__ pcnt) {
    int wid  = (blockIdx.x * blockDim.x + threadIdx.x) >> 6;
    int lane = threadIdx.x & 63;
    if (wid >= N_NODES) return;
    float2 v = ((const float2*)(X + (size_t)wid * FEA))[lane];
    float2 w = ((const float2*)nw)[lane];
    float dot = v.x * w.x + v.y * w.y;
#pragma unroll
    for (int off = 32; off; off >>= 1) dot += __shfl_down(dot, off);
    int b = batch[wid];
    if (lane == 0) {
        out_node[wid] = dot + nb[0];
        unsafeAtomicAdd(&pcnt[b], 1.0f);
    }
    unsafeAtomicAdd(&psum[b * FEA + lane * 2 + 0], v.x);
    unsafeAtomicAdd(&psum[b * FEA + lane * 2 + 1], v.y);
}

// ---------------- final MLP per graph ----------------
__global__ __launch_bounds__(256) void k_mlp(const float* __restrict__ psum,
                                             const float* __restrict__ pcnt,
                                             const float* __restrict__ w1,
                                             const float* __restrict__ b1,
                                             const float* __restrict__ w2,
                                             const float* __restrict__ b2,
                                             float* __restrict__ out) {
    __shared__ float fea[FEA];
    __shared__ float h1[AH];
    int g = blockIdx.x;
    float cnt = fmaxf(pcnt[g], 1.0f);
    if (threadIdx.x < FEA)
        fea[threadIdx.x] = psum[g * FEA + threadIdx.x] / cnt;
    __syncthreads();
    for (int j = threadIdx.x; j < AH; j += 256) {
        float acc = b1[j];
#pragma unroll 8
        for (int k = 0; k < FEA; ++k) acc += fea[k] * w1[k * AH + j];
        h1[j] = fmaxf(acc, 0.f);
    }
    __syncthreads();
    if (threadIdx.x < FEA) {
        int f = threadIdx.x;
        float acc = b2[f];
#pragma unroll 8
        for (int k = 0; k < AH; ++k) acc += h1[k] * w2[k * FEA + f];
        out[g * FEA + f] = acc;
    }
}

extern "C" void kernel_launch(void* const* d_in, const int* in_sizes, int n_in,
                              void* d_out, int out_size, void* d_ws, size_t ws_size,
                              hipStream_t stream) {
    const float* x     = (const float*)d_in[0];
    const int*   ei    = (const int*)d_in[1];
    const int*   batch = (const int*)d_in[2];
    const float* convW = (const float*)d_in[3];
    const float* convb = (const float*)d_in[4];
    const float* w1    = (const float*)d_in[5];
    const float* b1    = (const float*)d_in[6];
    const float* w2    = (const float*)d_in[7];
    const float* b2    = (const float*)d_in[8];
    const float* nw    = (const float*)d_in[9];
    const float* nb    = (const float*)d_in[10];
    float* out = (float*)d_out;

    // workspace layout (all 4-byte elements)
    char* wsb = (char*)d_ws;
    int*   deg    = (int*)wsb;                       // 50000
    float* dinv   = (float*)(wsb + 50048 * 4);       // 50000
    int*   rowptr = (int*)(wsb + 100096 * 4);        // 50001
    int*   cursor = (int*)(wsb + 150160 * 4);        // 50000
    int*   bsum   = (int*)(wsb + 200208 * 4);        // 196
    int*   boff   = (int*)(wsb + 200464 * 4);        // 196
    int*   eidx   = (int*)(wsb + 200720 * 4);        // 800000
    float* H      = (float*)(wsb + 1000768ll * 4);   // 6.4M
    float* X      = H + (size_t)N_NODES * FEA;       // 6.4M
    float* psum   = X + (size_t)N_NODES * FEA;       // 8192
    float* pcnt   = psum + NG * FEA;                 // 64

    const int* srcp = ei;
    const int* dstp = ei + N_EDGES;

    // ---- CSR build (once per call) ----
    hipMemsetAsync(deg, 0, N_NODES * sizeof(int), stream);
    k_deg<<<(N_EDGES + 255) / 256, 256, 0, stream>>>(dstp, deg);
    k_dinv<<<NBLK, 256, 0, stream>>>(deg, dinv);
    k_scan1<<<NBLK, 256, 0, stream>>>(deg, rowptr, bsum);
    k_scan2<<<1, 256, 0, stream>>>(bsum, boff);
    k_scan3<<<NBLK, 256, 0, stream>>>(rowptr, boff, cursor);
    k_fill<<<(N_EDGES + 255) / 256, 256, 0, stream>>>(srcp, dstp, cursor, eidx);

    // ---- GCN layers ----
    const float* xcur = x;
    for (int l = 0; l < NL; ++l) {
        k_gemm<<<512, 256, 0, stream>>>(xcur, convW + (size_t)l * FEA * FEA, dinv, H, N_NODES);
        k_gather<<<(N_NODES * 64 + 255) / 256, 256, 0, stream>>>(
            rowptr, eidx, dinv, H, convb + (size_t)l * FEA, X);
        xcur = X;
    }

    // ---- heads ----
    hipMemsetAsync(psum, 0, (NG * FEA + NG) * sizeof(float), stream);
    k_node_pool<<<(N_NODES * 64 + 255) / 256, 256, 0, stream>>>(X, batch, nw, nb, out, psum, pcnt);
    k_mlp<<<NG, 256, 0, stream>>>(psum, pcnt, w1, b1, w2, b2, out + N_NODES);
}

// Round 3
// 488.993 us; speedup vs baseline: 9.6391x; 1.8278x over previous
//
#include <hip/hip_runtime.h>

#define N_NODES 50000
#define N_EDGES 800000
#define FEA 128
#define NL 3
#define AH 512
#define NG 64
#define NBLK 196   // ceil(50000/256)

// ---------------- degree histogram (int) ----------------
__global__ void k_deg(const int* __restrict__ dst, int* __restrict__ deg) {
    int i = blockIdx.x * blockDim.x + threadIdx.x;
    if (i < N_EDGES) atomicAdd(&deg[dst[i]], 1);
}

__global__ void k_dinv(const int* __restrict__ deg, float* __restrict__ dinv) {
    int i = blockIdx.x * blockDim.x + threadIdx.x;
    if (i < N_NODES) dinv[i] = rsqrtf((float)deg[i] + 1.0f);
}

// ---------------- 3-kernel exclusive scan -> rowptr ----------------
__device__ __forceinline__ int block_scan_incl(int v, int* wsum) {
    int lane = threadIdx.x & 63, w = threadIdx.x >> 6;
    int s = v;
#pragma unroll
    for (int off = 1; off < 64; off <<= 1) {
        int t = __shfl_up(s, off);
        if (lane >= off) s += t;
    }
    if (lane == 63) wsum[w] = s;
    __syncthreads();
    int woff = 0;
    for (int k = 0; k < w; ++k) woff += wsum[k];
    return woff + s;  // block-wide inclusive
}

__global__ __launch_bounds__(256) void k_scan1(const int* __restrict__ deg,
                                               int* __restrict__ rowptr,
                                               int* __restrict__ bsum) {
    __shared__ int wsum[4];
    int i = blockIdx.x * 256 + threadIdx.x;
    int v = (i < N_NODES) ? deg[i] : 0;
    int incl = block_scan_incl(v, wsum);
    if (i < N_NODES) rowptr[i] = incl - v;  // local exclusive
    if (threadIdx.x == 255) bsum[blockIdx.x] = incl;
}

__global__ __launch_bounds__(256) void k_scan2(int* __restrict__ bsum,
                                               int* __restrict__ boff) {
    __shared__ int wsum[4];
    int v = (threadIdx.x < NBLK) ? bsum[threadIdx.x] : 0;
    int incl = block_scan_incl(v, wsum);
    if (threadIdx.x < NBLK) boff[threadIdx.x] = incl - v;
}

__global__ __launch_bounds__(256) void k_scan3(int* __restrict__ rowptr,
                                               const int* __restrict__ boff,
                                               int* __restrict__ cursor) {
    int i = blockIdx.x * 256 + threadIdx.x;
    if (i < N_NODES) {
        int r = rowptr[i] + boff[blockIdx.x];
        rowptr[i] = r;
        cursor[i] = r;
    }
    if (i == 0) rowptr[N_NODES] = N_EDGES;
}

// ---------------- CSR fill ----------------
__global__ void k_fill(const int* __restrict__ src, const int* __restrict__ dst,
                       int* __restrict__ cursor, int* __restrict__ eidx) {
    int e = blockIdx.x * blockDim.x + threadIdx.x;
    if (e < N_EDGES) {
        int p = atomicAdd(&cursor[dst[e]], 1);
        eidx[p] = src[e];
    }
}

// ---------------- graph boundaries from sorted batch ----------------
__global__ void k_bounds(const int* __restrict__ batch, int* __restrict__ gstart) {
    int i = blockIdx.x * blockDim.x + threadIdx.x;
    if (i >= N_NODES) return;
    int b = batch[i];
    int bp = (i == 0) ? -1 : batch[i - 1];
    for (int g = bp + 1; g <= b; ++g) gstart[g] = i;
    if (i == N_NODES - 1)
        for (int g = b + 1; g <= NG; ++g) gstart[g] = N_NODES;
}

// ---------------- GEMM: H' = dinv * (X @ W) ----------------
__global__ __launch_bounds__(256) void k_gemm(const float* __restrict__ X,
                                              const float* __restrict__ W,
                                              const float* __restrict__ dinv,
                                              float* __restrict__ H, int nrows) {
    __shared__ float Wl[FEA * FEA];   // 64 KiB
    __shared__ float Xs[8 * FEA];     // 4 KiB
    for (int i = threadIdx.x; i < FEA * FEA / 4; i += 256)
        ((float4*)Wl)[i] = ((const float4*)W)[i];
    __syncthreads();

    const int c4 = threadIdx.x & 31;
    const int rl = threadIdx.x >> 5;

    for (int r0 = blockIdx.x * 8; r0 < nrows; r0 += gridDim.x * 8) {
        int nr = min(8, nrows - r0);
        __syncthreads();
        {
            int rr = threadIdx.x >> 5, cc = threadIdx.x & 31;
            if (rr < nr)
                ((float4*)Xs)[threadIdx.x] =
                    ((const float4*)(X + (size_t)(r0 + rr) * FEA))[cc];
        }
        __syncthreads();
        if (rl < nr) {
            float4 acc = {0.f, 0.f, 0.f, 0.f};
            const float* xr = Xs + rl * FEA;
#pragma unroll 16
            for (int k = 0; k < FEA; ++k) {
                float xv = xr[k];
                float4 w = ((float4*)Wl)[k * 32 + c4];
                acc.x += xv * w.x; acc.y += xv * w.y;
                acc.z += xv * w.z; acc.w += xv * w.w;
            }
            float s = dinv[r0 + rl];
            acc.x *= s; acc.y *= s; acc.z *= s; acc.w *= s;
            ((float4*)(H + (size_t)(r0 + rl) * FEA))[c4] = acc;
        }
    }
}

// ---------------- gather: X[d] = relu(dinv[d]*(sum H'[s] + H'[d]) + b) ----------------
__global__ __launch_bounds__(256) void k_gather(const int* __restrict__ rowptr,
                                                const int* __restrict__ eidx,
                                                const float* __restrict__ dinv,
                                                const float* __restrict__ H,
                                                const float* __restrict__ b,
                                                float* __restrict__ X) {
    int node = (blockIdx.x * blockDim.x + threadIdx.x) >> 6;
    int lane = threadIdx.x & 63;
    if (node >= N_NODES) return;
    int r0 = rowptr[node], r1 = rowptr[node + 1];
    float2 acc = ((const float2*)(H + (size_t)node * FEA))[lane];  // self term
    for (int base = r0; base < r1; base += 64) {
        int cnt = min(64, r1 - base);
        int my_e = (lane < cnt) ? eidx[base + lane] : 0;
        for (int j = 0; j < cnt; ++j) {
            int s = __shfl(my_e, j);
            float2 h = ((const float2*)(H + (size_t)s * FEA))[lane];
            acc.x += h.x; acc.y += h.y;
        }
    }
    float di = dinv[node];
    float2 bb = ((const float2*)b)[lane];
    float2 o;
    o.x = fmaxf(acc.x * di + bb.x, 0.f);
    o.y = fmaxf(acc.y * di + bb.y, 0.f);
    ((float2*)(X + (size_t)node * FEA))[lane] = o;
}

// ---------------- per-graph pooled sums + node head (no atomics) ----------------
// 4 blocks per graph; block = g*4+p handles quarter p of graph g's node range.
__global__ __launch_bounds__(256) void k_graph(const float* __restrict__ X,
                                               const int* __restrict__ gstart,
                                               const float* __restrict__ nw,
                                               const float* __restrict__ nb,
                                               float* __restrict__ out_node,
                                               float* __restrict__ psum_part) {
    int g = blockIdx.x >> 2, p = blockIdx.x & 3;
    int s = gstart[g], e = gstart[g + 1];
    int len = e - s;
    int l4 = (len + 3) >> 2;
    int ps = s + p * l4, pe = min(ps + l4, e);
    int wave = threadIdx.x >> 6, lane = threadIdx.x & 63;
    float2 w = ((const float2*)nw)[lane];
    float nbv = nb[0];
    float2 acc = {0.f, 0.f};
    for (int node = ps + wave; node < pe; node += 4) {
        float2 v = ((const float2*)(X + (size_t)node * FEA))[lane];
        acc.x += v.x; acc.y += v.y;
        float dot = v.x * w.x + v.y * w.y;
#pragma unroll
        for (int off = 32; off; off >>= 1) dot += __shfl_down(dot, off);
        if (lane == 0) out_node[node] = dot + nbv;
    }
    __shared__ float lds[4 * FEA];
    lds[wave * FEA + lane * 2 + 0] = acc.x;
    lds[wave * FEA + lane * 2 + 1] = acc.y;
    __syncthreads();
    if (threadIdx.x < FEA) {
        float sum = lds[threadIdx.x] + lds[FEA + threadIdx.x] +
                    lds[2 * FEA + threadIdx.x] + lds[3 * FEA + threadIdx.x];
        psum_part[(size_t)blockIdx.x * FEA + threadIdx.x] = sum;
    }
}

// ---------------- final MLP per graph ----------------
__global__ __launch_bounds__(256) void k_mlp(const float* __restrict__ psum_part,
                                             const int* __restrict__ gstart,
                                             const float* __restrict__ w1,
                                             const float* __restrict__ b1,
                                             const float* __restrict__ w2,
                                             const float* __restrict__ b2,
                                             float* __restrict__ out) {
    __shared__ float fea[FEA];
    __shared__ float h1[AH];
    int g = blockIdx.x;
    float cnt = fmaxf((float)(gstart[g + 1] - gstart[g]), 1.0f);
    if (threadIdx.x < FEA) {
        const float* pp = psum_part + (size_t)g * 4 * FEA + threadIdx.x;
        fea[threadIdx.x] = (pp[0] + pp[FEA] + pp[2 * FEA] + pp[3 * FEA]) / cnt;
    }
    __syncthreads();
    for (int j = threadIdx.x; j < AH; j += 256) {
        float acc = b1[j];
#pragma unroll 8
        for (int k = 0; k < FEA; ++k) acc += fea[k] * w1[k * AH + j];
        h1[j] = fmaxf(acc, 0.f);
    }
    __syncthreads();
    if (threadIdx.x < FEA) {
        int f = threadIdx.x;
        float acc = b2[f];
#pragma unroll 8
        for (int k = 0; k < AH; ++k) acc += h1[k] * w2[k * FEA + f];
        out[g * FEA + f] = acc;
    }
}

extern "C" void kernel_launch(void* const* d_in, const int* in_sizes, int n_in,
                              void* d_out, int out_size, void* d_ws, size_t ws_size,
                              hipStream_t stream) {
    const float* x     = (const float*)d_in[0];
    const int*   ei    = (const int*)d_in[1];
    const int*   batch = (const int*)d_in[2];
    const float* convW = (const float*)d_in[3];
    const float* convb = (const float*)d_in[4];
    const float* w1    = (const float*)d_in[5];
    const float* b1    = (const float*)d_in[6];
    const float* w2    = (const float*)d_in[7];
    const float* b2    = (const float*)d_in[8];
    const float* nw    = (const float*)d_in[9];
    const float* nb    = (const float*)d_in[10];
    float* out = (float*)d_out;

    // workspace layout (4-byte element offsets)
    char* wsb = (char*)d_ws;
    int*   deg    = (int*)wsb;                        // 50000
    float* dinv   = (float*)(wsb + 50048ll * 4);      // 50000
    int*   rowptr = (int*)(wsb + 100096ll * 4);       // 50001
    int*   cursor = (int*)(wsb + 150160ll * 4);       // 50000
    int*   bsum   = (int*)(wsb + 200208ll * 4);       // 196
    int*   boff   = (int*)(wsb + 200464ll * 4);       // 196
    int*   gstart = (int*)(wsb + 200720ll * 4);       // 65
    int*   eidx   = (int*)(wsb + 200800ll * 4);       // 800000
    float* H      = (float*)(wsb + 1000832ll * 4);    // 6.4M
    float* X      = H + (size_t)N_NODES * FEA;        // 6.4M
    float* psum_part = X + (size_t)N_NODES * FEA;     // 256*128

    const int* srcp = ei;
    const int* dstp = ei + N_EDGES;

    // ---- CSR build + boundaries (once per call) ----
    hipMemsetAsync(deg, 0, N_NODES * sizeof(int), stream);
    k_deg<<<(N_EDGES + 255) / 256, 256, 0, stream>>>(dstp, deg);
    k_dinv<<<NBLK, 256, 0, stream>>>(deg, dinv);
    k_scan1<<<NBLK, 256, 0, stream>>>(deg, rowptr, bsum);
    k_scan2<<<1, 256, 0, stream>>>(bsum, boff);
    k_scan3<<<NBLK, 256, 0, stream>>>(rowptr, boff, cursor);
    k_fill<<<(N_EDGES + 255) / 256, 256, 0, stream>>>(srcp, dstp, cursor, eidx);
    k_bounds<<<NBLK, 256, 0, stream>>>(batch, gstart);

    // ---- GCN layers ----
    const float* xcur = x;
    for (int l = 0; l < NL; ++l) {
        k_gemm<<<512, 256, 0, stream>>>(xcur, convW + (size_t)l * FEA * FEA, dinv, H, N_NODES);
        k_gather<<<(N_NODES * 64 + 255) / 256, 256, 0, stream>>>(
            rowptr, eidx, dinv, H, convb + (size_t)l * FEA, X);
        xcur = X;
    }

    // ---- heads ----
    k_graph<<<NG * 4, 256, 0, stream>>>(X, gstart, nw, nb, out, psum_part);
    k_mlp<<<NG, 256, 0, stream>>>(psum_part, gstart, w1, b1, w2, b2, out + N_NODES);
}

// Round 4
// 468.534 us; speedup vs baseline: 10.0600x; 1.0437x over previous
//
#include <hip/hip_runtime.h>

#define N_NODES 50000
#define N_EDGES 800000
#define FEA 128
#define NL 3
#define AH 512
#define NG 64
#define NBLK 196   // ceil(50000/256)

// ---------------- degree histogram (int) ----------------
__global__ void k_deg(const int* __restrict__ dst, int* __restrict__ deg) {
    int i = blockIdx.x * blockDim.x + threadIdx.x;
    if (i < N_EDGES) atomicAdd(&deg[dst[i]], 1);
}

__global__ void k_dinv(const int* __restrict__ deg, float* __restrict__ dinv) {
    int i = blockIdx.x * blockDim.x + threadIdx.x;
    if (i < N_NODES) dinv[i] = rsqrtf((float)deg[i] + 1.0f);
}

// ---------------- 3-kernel exclusive scan -> rowptr ----------------
__device__ __forceinline__ int block_scan_incl(int v, int* wsum) {
    int lane = threadIdx.x & 63, w = threadIdx.x >> 6;
    int s = v;
#pragma unroll
    for (int off = 1; off < 64; off <<= 1) {
        int t = __shfl_up(s, off);
        if (lane >= off) s += t;
    }
    if (lane == 63) wsum[w] = s;
    __syncthreads();
    int woff = 0;
    for (int k = 0; k < w; ++k) woff += wsum[k];
    return woff + s;  // block-wide inclusive
}

__global__ __launch_bounds__(256) void k_scan1(const int* __restrict__ deg,
                                               int* __restrict__ rowptr,
                                               int* __restrict__ bsum) {
    __shared__ int wsum[4];
    int i = blockIdx.x * 256 + threadIdx.x;
    int v = (i < N_NODES) ? deg[i] : 0;
    int incl = block_scan_incl(v, wsum);
    if (i < N_NODES) rowptr[i] = incl - v;  // local exclusive
    if (threadIdx.x == 255) bsum[blockIdx.x] = incl;
}

__global__ __launch_bounds__(256) void k_scan2(int* __restrict__ bsum,
                                               int* __restrict__ boff) {
    __shared__ int wsum[4];
    int v = (threadIdx.x < NBLK) ? bsum[threadIdx.x] : 0;
    int incl = block_scan_incl(v, wsum);
    if (threadIdx.x < NBLK) boff[threadIdx.x] = incl - v;
}

__global__ __launch_bounds__(256) void k_scan3(int* __restrict__ rowptr,
                                               const int* __restrict__ boff,
                                               int* __restrict__ cursor) {
    int i = blockIdx.x * 256 + threadIdx.x;
    if (i < N_NODES) {
        int r = rowptr[i] + boff[blockIdx.x];
        rowptr[i] = r;
        cursor[i] = r;
    }
    if (i == 0) rowptr[N_NODES] = N_EDGES;
}

// ---------------- CSR fill ----------------
__global__ void k_fill(const int* __restrict__ src, const int* __restrict__ dst,
                       int* __restrict__ cursor, int* __restrict__ eidx) {
    int e = blockIdx.x * blockDim.x + threadIdx.x;
    if (e < N_EDGES) {
        int p = atomicAdd(&cursor[dst[e]], 1);
        eidx[p] = src[e];
    }
}

// ---------------- graph boundaries from sorted batch ----------------
__global__ void k_bounds(const int* __restrict__ batch, int* __restrict__ gstart) {
    int i = blockIdx.x * blockDim.x + threadIdx.x;
    if (i >= N_NODES) return;
    int b = batch[i];
    int bp = (i == 0) ? -1 : batch[i - 1];
    for (int g = bp + 1; g <= b; ++g) gstart[g] = i;
    if (i == N_NODES - 1)
        for (int g = b + 1; g <= NG; ++g) gstart[g] = N_NODES;
}

// ---------------- GEMM: H' = dinv * (X @ W) ----------------
__global__ __launch_bounds__(256) void k_gemm(const float* __restrict__ X,
                                              const float* __restrict__ W,
                                              const float* __restrict__ dinv,
                                              float* __restrict__ H, int nrows) {
    __shared__ float Wl[FEA * FEA];   // 64 KiB
    __shared__ float Xs[8 * FEA];     // 4 KiB
    for (int i = threadIdx.x; i < FEA * FEA / 4; i += 256)
        ((float4*)Wl)[i] = ((const float4*)W)[i];
    __syncthreads();

    const int c4 = threadIdx.x & 31;
    const int rl = threadIdx.x >> 5;

    for (int r0 = blockIdx.x * 8; r0 < nrows; r0 += gridDim.x * 8) {
        int nr = min(8, nrows - r0);
        __syncthreads();
        {
            int rr = threadIdx.x >> 5, cc = threadIdx.x & 31;
            if (rr < nr)
                ((float4*)Xs)[threadIdx.x] =
                    ((const float4*)(X + (size_t)(r0 + rr) * FEA))[cc];
        }
        __syncthreads();
        if (rl < nr) {
            float4 acc = {0.f, 0.f, 0.f, 0.f};
            const float* xr = Xs + rl * FEA;
#pragma unroll 16
            for (int k = 0; k < FEA; ++k) {
                float xv = xr[k];
                float4 w = ((float4*)Wl)[k * 32 + c4];
                acc.x += xv * w.x; acc.y += xv * w.y;
                acc.z += xv * w.z; acc.w += xv * w.w;
            }
            float s = dinv[r0 + rl];
            acc.x *= s; acc.y *= s; acc.z *= s; acc.w *= s;
            ((float4*)(H + (size_t)(r0 + rl) * FEA))[c4] = acc;
        }
    }
}

// ---------------- gather: X[d] = relu(dinv[d]*(sum H'[s] + H'[d]) + b) ----------------
// 32 threads per node (thread = float4 chunk), edge loop unrolled 4-deep
// with independent accumulators for memory-level parallelism.
__global__ __launch_bounds__(256) void k_gather(const int* __restrict__ rowptr,
                                                const int* __restrict__ eidx,
                                                const float* __restrict__ dinv,
                                                const float* __restrict__ H,
                                                const float* __restrict__ b,
                                                float* __restrict__ X) {
    int t = blockIdx.x * 256 + threadIdx.x;
    int node = t >> 5;
    int c4 = t & 31;
    if (node >= N_NODES) return;
    const float4* H4 = (const float4*)H;
    int r0 = rowptr[node], r1 = rowptr[node + 1];

    float4 a0 = H4[(size_t)node * 32 + c4];  // self term
    float4 a1 = {0.f, 0.f, 0.f, 0.f};
    float4 a2 = {0.f, 0.f, 0.f, 0.f};
    float4 a3 = {0.f, 0.f, 0.f, 0.f};

    int j = r0;
    for (; j + 4 <= r1; j += 4) {
        int s0 = eidx[j + 0], s1 = eidx[j + 1];
        int s2 = eidx[j + 2], s3 = eidx[j + 3];
        float4 h0 = H4[(size_t)s0 * 32 + c4];
        float4 h1 = H4[(size_t)s1 * 32 + c4];
        float4 h2 = H4[(size_t)s2 * 32 + c4];
        float4 h3 = H4[(size_t)s3 * 32 + c4];
        a0.x += h0.x; a0.y += h0.y; a0.z += h0.z; a0.w += h0.w;
        a1.x += h1.x; a1.y += h1.y; a1.z += h1.z; a1.w += h1.w;
        a2.x += h2.x; a2.y += h2.y; a2.z += h2.z; a2.w += h2.w;
        a3.x += h3.x; a3.y += h3.y; a3.z += h3.z; a3.w += h3.w;
    }
    for (; j < r1; ++j) {
        int s = eidx[j];
        float4 h = H4[(size_t)s * 32 + c4];
        a0.x += h.x; a0.y += h.y; a0.z += h.z; a0.w += h.w;
    }
    float di = dinv[node];
    float4 bb = ((const float4*)b)[c4];
    float4 o;
    o.x = fmaxf((a0.x + a1.x + a2.x + a3.x) * di + bb.x, 0.f);
    o.y = fmaxf((a0.y + a1.y + a2.y + a3.y) * di + bb.y, 0.f);
    o.z = fmaxf((a0.z + a1.z + a2.z + a3.z) * di + bb.z, 0.f);
    o.w = fmaxf((a0.w + a1.w + a2.w + a3.w) * di + bb.w, 0.f);
    ((float4*)X)[(size_t)node * 32 + c4] = o;
}

// ---------------- per-graph pooled sums + node head (no atomics) ----------------
__global__ __launch_bounds__(256) void k_graph(const float* __restrict__ X,
                                               const int* __restrict__ gstart,
                                               const float* __restrict__ nw,
                                               const float* __restrict__ nb,
                                               float* __restrict__ out_node,
                                               float* __restrict__ psum_part) {
    int g = blockIdx.x >> 2, p = blockIdx.x & 3;
    int s = gstart[g], e = gstart[g + 1];
    int len = e - s;
    int l4 = (len + 3) >> 2;
    int ps = s + p * l4, pe = min(ps + l4, e);
    int wave = threadIdx.x >> 6, lane = threadIdx.x & 63;
    float2 w = ((const float2*)nw)[lane];
    float nbv = nb[0];
    float2 acc = {0.f, 0.f};
    for (int node = ps + wave; node < pe; node += 4) {
        float2 v = ((const float2*)(X + (size_t)node * FEA))[lane];
        acc.x += v.x; acc.y += v.y;
        float dot = v.x * w.x + v.y * w.y;
#pragma unroll
        for (int off = 32; off; off >>= 1) dot += __shfl_down(dot, off);
        if (lane == 0) out_node[node] = dot + nbv;
    }
    __shared__ float lds[4 * FEA];
    lds[wave * FEA + lane * 2 + 0] = acc.x;
    lds[wave * FEA + lane * 2 + 1] = acc.y;
    __syncthreads();
    if (threadIdx.x < FEA) {
        float sum = lds[threadIdx.x] + lds[FEA + threadIdx.x] +
                    lds[2 * FEA + threadIdx.x] + lds[3 * FEA + threadIdx.x];
        psum_part[(size_t)blockIdx.x * FEA + threadIdx.x] = sum;
    }
}

// ---------------- final MLP per graph ----------------
__global__ __launch_bounds__(256) void k_mlp(const float* __restrict__ psum_part,
                                             const int* __restrict__ gstart,
                                             const float* __restrict__ w1,
                                             const float* __restrict__ b1,
                                             const float* __restrict__ w2,
                                             const float* __restrict__ b2,
                                             float* __restrict__ out) {
    __shared__ float fea[FEA];
    __shared__ float h1[AH];
    int g = blockIdx.x;
    float cnt = fmaxf((float)(gstart[g + 1] - gstart[g]), 1.0f);
    if (threadIdx.x < FEA) {
        const float* pp = psum_part + (size_t)g * 4 * FEA + threadIdx.x;
        fea[threadIdx.x] = (pp[0] + pp[FEA] + pp[2 * FEA] + pp[3 * FEA]) / cnt;
    }
    __syncthreads();
    for (int j = threadIdx.x; j < AH; j += 256) {
        float acc = b1[j];
#pragma unroll 8
        for (int k = 0; k < FEA; ++k) acc += fea[k] * w1[k * AH + j];
        h1[j] = fmaxf(acc, 0.f);
    }
    __syncthreads();
    if (threadIdx.x < FEA) {
        int f = threadIdx.x;
        float acc = b2[f];
#pragma unroll 8
        for (int k = 0; k < AH; ++k) acc += h1[k] * w2[k * FEA + f];
        out[g * FEA + f] = acc;
    }
}

extern "C" void kernel_launch(void* const* d_in, const int* in_sizes, int n_in,
                              void* d_out, int out_size, void* d_ws, size_t ws_size,
                              hipStream_t stream) {
    const float* x     = (const float*)d_in[0];
    const int*   ei    = (const int*)d_in[1];
    const int*   batch = (const int*)d_in[2];
    const float* convW = (const float*)d_in[3];
    const float* convb = (const float*)d_in[4];
    const float* w1    = (const float*)d_in[5];
    const float* b1    = (const float*)d_in[6];
    const float* w2    = (const float*)d_in[7];
    const float* b2    = (const float*)d_in[8];
    const float* nw    = (const float*)d_in[9];
    const float* nb    = (const float*)d_in[10];
    float* out = (float*)d_out;

    // workspace layout (4-byte element offsets)
    char* wsb = (char*)d_ws;
    int*   deg    = (int*)wsb;                        // 50000
    float* dinv   = (float*)(wsb + 50048ll * 4);      // 50000
    int*   rowptr = (int*)(wsb + 100096ll * 4);       // 50001
    int*   cursor = (int*)(wsb + 150160ll * 4);       // 50000
    int*   bsum   = (int*)(wsb + 200208ll * 4);       // 196
    int*   boff   = (int*)(wsb + 200464ll * 4);       // 196
    int*   gstart = (int*)(wsb + 200720ll * 4);       // 65
    int*   eidx   = (int*)(wsb + 200800ll * 4);       // 800000
    float* H      = (float*)(wsb + 1000832ll * 4);    // 6.4M
    float* X      = H + (size_t)N_NODES * FEA;        // 6.4M
    float* psum_part = X + (size_t)N_NODES * FEA;     // 256*128

    const int* srcp = ei;
    const int* dstp = ei + N_EDGES;

    // ---- CSR build + boundaries (once per call) ----
    hipMemsetAsync(deg, 0, N_NODES * sizeof(int), stream);
    k_deg<<<(N_EDGES + 255) / 256, 256, 0, stream>>>(dstp, deg);
    k_dinv<<<NBLK, 256, 0, stream>>>(deg, dinv);
    k_scan1<<<NBLK, 256, 0, stream>>>(deg, rowptr, bsum);
    k_scan2<<<1, 256, 0, stream>>>(bsum, boff);
    k_scan3<<<NBLK, 256, 0, stream>>>(rowptr, boff, cursor);
    k_fill<<<(N_EDGES + 255) / 256, 256, 0, stream>>>(srcp, dstp, cursor, eidx);
    k_bounds<<<NBLK, 256, 0, stream>>>(batch, gstart);

    // ---- GCN layers ----
    const float* xcur = x;
    for (int l = 0; l < NL; ++l) {
        k_gemm<<<512, 256, 0, stream>>>(xcur, convW + (size_t)l * FEA * FEA, dinv, H, N_NODES);
        k_gather<<<(N_NODES * 32 + 255) / 256, 256, 0, stream>>>(
            rowptr, eidx, dinv, H, convb + (size_t)l * FEA, X);
        xcur = X;
    }

    // ---- heads ----
    k_graph<<<NG * 4, 256, 0, stream>>>(X, gstart, nw, nb, out, psum_part);
    k_mlp<<<NG, 256, 0, stream>>>(psum_part, gstart, w1, b1, w2, b2, out + N_NODES);
}

// Round 5
// 331.267 us; speedup vs baseline: 14.2285x; 1.4144x over previous
//
#include <hip/hip_runtime.h>

#define N_NODES 50000
#define N_EDGES 800000
#define FEA 128
#define NL 3
#define AH 512
#define NG 64
#define NBLK 196   // ceil(50000/256)

typedef short bf16x8 __attribute__((ext_vector_type(8)));
typedef float f32x4 __attribute__((ext_vector_type(4)));

__device__ __forceinline__ ushort f2bf(float f) {   // RTN-even
    uint u = __float_as_uint(f);
    uint r = u + 0x7FFFu + ((u >> 16) & 1u);
    return (ushort)(r >> 16);
}
__device__ __forceinline__ float bf2f(ushort u) {
    return __uint_as_float((uint)u << 16);
}

// ---------------- degree histogram (int) ----------------
__global__ void k_deg(const int* __restrict__ dst, int* __restrict__ deg) {
    int i = blockIdx.x * blockDim.x + threadIdx.x;
    if (i < N_EDGES) atomicAdd(&deg[dst[i]], 1);
}

__global__ void k_dinv(const int* __restrict__ deg, float* __restrict__ dinv) {
    int i = blockIdx.x * blockDim.x + threadIdx.x;
    if (i < N_NODES) dinv[i] = rsqrtf((float)deg[i] + 1.0f);
}

// ---------------- 3-kernel exclusive scan -> rowptr ----------------
__device__ __forceinline__ int block_scan_incl(int v, int* wsum) {
    int lane = threadIdx.x & 63, w = threadIdx.x >> 6;
    int s = v;
#pragma unroll
    for (int off = 1; off < 64; off <<= 1) {
        int t = __shfl_up(s, off);
        if (lane >= off) s += t;
    }
    if (lane == 63) wsum[w] = s;
    __syncthreads();
    int woff = 0;
    for (int k = 0; k < w; ++k) woff += wsum[k];
    return woff + s;  // block-wide inclusive
}

__global__ __launch_bounds__(256) void k_scan1(const int* __restrict__ deg,
                                               int* __restrict__ rowptr,
                                               int* __restrict__ bsum) {
    __shared__ int wsum[4];
    int i = blockIdx.x * 256 + threadIdx.x;
    int v = (i < N_NODES) ? deg[i] : 0;
    int incl = block_scan_incl(v, wsum);
    if (i < N_NODES) rowptr[i] = incl - v;  // local exclusive
    if (threadIdx.x == 255) bsum[blockIdx.x] = incl;
}

__global__ __launch_bounds__(256) void k_scan2(int* __restrict__ bsum,
                                               int* __restrict__ boff) {
    __shared__ int wsum[4];
    int v = (threadIdx.x < NBLK) ? bsum[threadIdx.x] : 0;
    int incl = block_scan_incl(v, wsum);
    if (threadIdx.x < NBLK) boff[threadIdx.x] = incl - v;
}

__global__ __launch_bounds__(256) void k_scan3(int* __restrict__ rowptr,
                                               const int* __restrict__ boff,
                                               int* __restrict__ cursor) {
    int i = blockIdx.x * 256 + threadIdx.x;
    if (i < N_NODES) {
        int r = rowptr[i] + boff[blockIdx.x];
        rowptr[i] = r;
        cursor[i] = r;
    }
    if (i == 0) rowptr[N_NODES] = N_EDGES;
}

// ---------------- CSR fill ----------------
__global__ void k_fill(const int* __restrict__ src, const int* __restrict__ dst,
                       int* __restrict__ cursor, int* __restrict__ eidx) {
    int e = blockIdx.x * blockDim.x + threadIdx.x;
    if (e < N_EDGES) {
        int p = atomicAdd(&cursor[dst[e]], 1);
        eidx[p] = src[e];
    }
}

// ---------------- graph boundaries from sorted batch ----------------
__global__ void k_bounds(const int* __restrict__ batch, int* __restrict__ gstart) {
    int i = blockIdx.x * blockDim.x + threadIdx.x;
    if (i >= N_NODES) return;
    int b = batch[i];
    int bp = (i == 0) ? -1 : batch[i - 1];
    for (int g = bp + 1; g <= b; ++g) gstart[g] = i;
    if (i == N_NODES - 1)
        for (int g = b + 1; g <= NG; ++g) gstart[g] = N_NODES;
}

// ---------------- MFMA GEMM: H'(bf16) = dinv * (X @ W) ----------------
// Split-bf16: X=xh+xl, W=wh+wl; acc = xh@wh + xh@wl + xl@wh (f32 MFMA acc).
// Block: 256 thr = 4 waves; each wave owns 32 cols (2 16-col tiles); block
// covers 16 rows x 128 cols per iteration. B-frags register-resident.
// Layouts (16x16x32 bf16): A: row=lane&15, k=(lane>>4)*8+j
//                          B: col=lane&15, k=(lane>>4)*8+j
//                          D: col=lane&15, row=(lane>>4)*4+reg  [m89]
__global__ __launch_bounds__(256) void k_gemm(const float* __restrict__ X,
                                              const float* __restrict__ W,
                                              const float* __restrict__ dinv,
                                              ushort* __restrict__ H) {
    const int wv = threadIdx.x >> 6;
    const int lane = threadIdx.x & 63;
    const int lr = lane & 15;
    const int lk = lane >> 4;

    bf16x8 bhi[2][4], blo[2][4];
#pragma unroll
    for (int ct = 0; ct < 2; ++ct) {
        int col = wv * 32 + ct * 16 + lr;
#pragma unroll
        for (int kf = 0; kf < 4; ++kf) {
            int k0 = kf * 32 + lk * 8;
#pragma unroll
            for (int j = 0; j < 8; ++j) {
                float w = W[(size_t)(k0 + j) * FEA + col];
                ushort h = f2bf(w);
                bhi[ct][kf][j] = (short)h;
                blo[ct][kf][j] = (short)f2bf(w - bf2f(h));
            }
        }
    }

    for (int rt = blockIdx.x; rt < N_NODES / 16; rt += gridDim.x) {
        int r0 = rt * 16;
        const float* xrow = X + (size_t)(r0 + lr) * FEA;
        bf16x8 ahi[4], alo[4];
#pragma unroll
        for (int kf = 0; kf < 4; ++kf) {
            int k0 = kf * 32 + lk * 8;
            float4 u0 = *(const float4*)(xrow + k0);
            float4 u1 = *(const float4*)(xrow + k0 + 4);
            float xs[8] = {u0.x, u0.y, u0.z, u0.w, u1.x, u1.y, u1.z, u1.w};
#pragma unroll
            for (int j = 0; j < 8; ++j) {
                ushort h = f2bf(xs[j]);
                ahi[kf][j] = (short)h;
                alo[kf][j] = (short)f2bf(xs[j] - bf2f(h));
            }
        }
        f32x4 acc0 = {0.f, 0.f, 0.f, 0.f};
        f32x4 acc1 = {0.f, 0.f, 0.f, 0.f};
#pragma unroll
        for (int kf = 0; kf < 4; ++kf) {
            acc0 = __builtin_amdgcn_mfma_f32_16x16x32_bf16(ahi[kf], bhi[0][kf], acc0, 0, 0, 0);
            acc0 = __builtin_amdgcn_mfma_f32_16x16x32_bf16(ahi[kf], blo[0][kf], acc0, 0, 0, 0);
            acc0 = __builtin_amdgcn_mfma_f32_16x16x32_bf16(alo[kf], bhi[0][kf], acc0, 0, 0, 0);
            acc1 = __builtin_amdgcn_mfma_f32_16x16x32_bf16(ahi[kf], bhi[1][kf], acc1, 0, 0, 0);
            acc1 = __builtin_amdgcn_mfma_f32_16x16x32_bf16(ahi[kf], blo[1][kf], acc1, 0, 0, 0);
            acc1 = __builtin_amdgcn_mfma_f32_16x16x32_bf16(alo[kf], bhi[1][kf], acc1, 0, 0, 0);
        }
#pragma unroll
        for (int reg = 0; reg < 4; ++reg) {
            int orow = r0 + lk * 4 + reg;
            float s = dinv[orow];
            H[(size_t)orow * FEA + wv * 32 + lr]      = f2bf(acc0[reg] * s);
            H[(size_t)orow * FEA + wv * 32 + 16 + lr] = f2bf(acc1[reg] * s);
        }
    }
}

// ---------------- gather: X[d] = relu(dinv[d]*(sum H'[s] + H'[d]) + b) ----------------
// 16 threads per node; thread = 8 features (one 16B bf16x8 chunk).
__global__ __launch_bounds__(256) void k_gather(const int* __restrict__ rowptr,
                                                const int* __restrict__ eidx,
                                                const float* __restrict__ dinv,
                                                const ushort* __restrict__ H,
                                                const float* __restrict__ b,
                                                float* __restrict__ X) {
    int t = blockIdx.x * 256 + threadIdx.x;
    int node = t >> 4;
    int c8 = t & 15;
    if (node >= N_NODES) return;
    const uint4* H4 = (const uint4*)H;  // 16 x uint4 per row
    int r0 = rowptr[node], r1 = rowptr[node + 1];

    float a[8] = {0.f, 0.f, 0.f, 0.f, 0.f, 0.f, 0.f, 0.f};
#define ACC8(u)                                                              \
    do {                                                                     \
        a[0] += __uint_as_float((u).x << 16);                                \
        a[1] += __uint_as_float((u).x & 0xffff0000u);                        \
        a[2] += __uint_as_float((u).y << 16);                                \
        a[3] += __uint_as_float((u).y & 0xffff0000u);                        \
        a[4] += __uint_as_float((u).z << 16);                                \
        a[5] += __uint_as_float((u).z & 0xffff0000u);                        \
        a[6] += __uint_as_float((u).w << 16);                                \
        a[7] += __uint_as_float((u).w & 0xffff0000u);                        \
    } while (0)

    uint4 sv = H4[(size_t)node * 16 + c8];  // self term
    ACC8(sv);

    int j = r0;
    for (; j + 4 <= r1; j += 4) {
        int s0 = eidx[j + 0], s1 = eidx[j + 1];
        int s2 = eidx[j + 2], s3 = eidx[j + 3];
        uint4 h0 = H4[(size_t)s0 * 16 + c8];
        uint4 h1 = H4[(size_t)s1 * 16 + c8];
        uint4 h2 = H4[(size_t)s2 * 16 + c8];
        uint4 h3 = H4[(size_t)s3 * 16 + c8];
        ACC8(h0); ACC8(h1); ACC8(h2); ACC8(h3);
    }
    for (; j < r1; ++j) {
        uint4 h = H4[(size_t)eidx[j] * 16 + c8];
        ACC8(h);
    }
#undef ACC8

    float di = dinv[node];
    const float4* b4 = (const float4*)b;
    float4 bb0 = b4[c8 * 2], bb1 = b4[c8 * 2 + 1];
    float4 o0, o1;
    o0.x = fmaxf(a[0] * di + bb0.x, 0.f);
    o0.y = fmaxf(a[1] * di + bb0.y, 0.f);
    o0.z = fmaxf(a[2] * di + bb0.z, 0.f);
    o0.w = fmaxf(a[3] * di + bb0.w, 0.f);
    o1.x = fmaxf(a[4] * di + bb1.x, 0.f);
    o1.y = fmaxf(a[5] * di + bb1.y, 0.f);
    o1.z = fmaxf(a[6] * di + bb1.z, 0.f);
    o1.w = fmaxf(a[7] * di + bb1.w, 0.f);
    ((float4*)X)[(size_t)node * 32 + c8 * 2 + 0] = o0;
    ((float4*)X)[(size_t)node * 32 + c8 * 2 + 1] = o1;
}

// ---------------- per-graph pooled sums + node head (no atomics) ----------------
__global__ __launch_bounds__(256) void k_graph(const float* __restrict__ X,
                                               const int* __restrict__ gstart,
                                               const float* __restrict__ nw,
                                               const float* __restrict__ nb,
                                               float* __restrict__ out_node,
                                               float* __restrict__ psum_part) {
    int g = blockIdx.x >> 2, p = blockIdx.x & 3;
    int s = gstart[g], e = gstart[g + 1];
    int len = e - s;
    int l4 = (len + 3) >> 2;
    int ps = s + p * l4, pe = min(ps + l4, e);
    int wave = threadIdx.x >> 6, lane = threadIdx.x & 63;
    float2 w = ((const float2*)nw)[lane];
    float nbv = nb[0];
    float2 acc = {0.f, 0.f};
    for (int node = ps + wave; node < pe; node += 4) {
        float2 v = ((const float2*)(X + (size_t)node * FEA))[lane];
        acc.x += v.x; acc.y += v.y;
        float dot = v.x * w.x + v.y * w.y;
#pragma unroll
        for (int off = 32; off; off >>= 1) dot += __shfl_down(dot, off);
        if (lane == 0) out_node[node] = dot + nbv;
    }
    __shared__ float lds[4 * FEA];
    lds[wave * FEA + lane * 2 + 0] = acc.x;
    lds[wave * FEA + lane * 2 + 1] = acc.y;
    __syncthreads();
    if (threadIdx.x < FEA) {
        float sum = lds[threadIdx.x] + lds[FEA + threadIdx.x] +
                    lds[2 * FEA + threadIdx.x] + lds[3 * FEA + threadIdx.x];
        psum_part[(size_t)blockIdx.x * FEA + threadIdx.x] = sum;
    }
}

// ---------------- final MLP per graph ----------------
__global__ __launch_bounds__(256) void k_mlp(const float* __restrict__ psum_part,
                                             const int* __restrict__ gstart,
                                             const float* __restrict__ w1,
                                             const float* __restrict__ b1,
                                             const float* __restrict__ w2,
                                             const float* __restrict__ b2,
                                             float* __restrict__ out) {
    __shared__ float fea[FEA];
    __shared__ float h1[AH];
    int g = blockIdx.x;
    float cnt = fmaxf((float)(gstart[g + 1] - gstart[g]), 1.0f);
    if (threadIdx.x < FEA) {
        const float* pp = psum_part + (size_t)g * 4 * FEA + threadIdx.x;
        fea[threadIdx.x] = (pp[0] + pp[FEA] + pp[2 * FEA] + pp[3 * FEA]) / cnt;
    }
    __syncthreads();
    for (int j = threadIdx.x; j < AH; j += 256) {
        float acc = b1[j];
#pragma unroll 8
        for (int k = 0; k < FEA; ++k) acc += fea[k] * w1[k * AH + j];
        h1[j] = fmaxf(acc, 0.f);
    }
    __syncthreads();
    if (threadIdx.x < FEA) {
        int f = threadIdx.x;
        float acc = b2[f];
#pragma unroll 8
        for (int k = 0; k < AH; ++k) acc += h1[k] * w2[k * FEA + f];
        out[g * FEA + f] = acc;
    }
}

extern "C" void kernel_launch(void* const* d_in, const int* in_sizes, int n_in,
                              void* d_out, int out_size, void* d_ws, size_t ws_size,
                              hipStream_t stream) {
    const float* x     = (const float*)d_in[0];
    const int*   ei    = (const int*)d_in[1];
    const int*   batch = (const int*)d_in[2];
    const float* convW = (const float*)d_in[3];
    const float* convb = (const float*)d_in[4];
    const float* w1    = (const float*)d_in[5];
    const float* b1    = (const float*)d_in[6];
    const float* w2    = (const float*)d_in[7];
    const float* b2    = (const float*)d_in[8];
    const float* nw    = (const float*)d_in[9];
    const float* nb    = (const float*)d_in[10];
    float* out = (float*)d_out;

    // workspace layout (4-byte element offsets)
    char* wsb = (char*)d_ws;
    int*   deg    = (int*)wsb;                        // 50000
    float* dinv   = (float*)(wsb + 50048ll * 4);      // 50000
    int*   rowptr = (int*)(wsb + 100096ll * 4);       // 50001
    int*   cursor = (int*)(wsb + 150160ll * 4);       // 50000
    int*   bsum   = (int*)(wsb + 200208ll * 4);       // 196
    int*   boff   = (int*)(wsb + 200464ll * 4);       // 196
    int*   gstart = (int*)(wsb + 200720ll * 4);       // 65
    int*   eidx   = (int*)(wsb + 200800ll * 4);       // 800000
    ushort* H     = (ushort*)(wsb + 1000832ll * 4);   // 6.4M bf16 (12.8MB)
    float* X      = (float*)(wsb + 1000832ll * 4 + (size_t)N_NODES * FEA * 2);
    float* psum_part = X + (size_t)N_NODES * FEA;     // 256*128

    const int* srcp = ei;
    const int* dstp = ei + N_EDGES;

    // ---- CSR build + boundaries (once per call) ----
    hipMemsetAsync(deg, 0, N_NODES * sizeof(int), stream);
    k_deg<<<(N_EDGES + 255) / 256, 256, 0, stream>>>(dstp, deg);
    k_dinv<<<NBLK, 256, 0, stream>>>(deg, dinv);
    k_scan1<<<NBLK, 256, 0, stream>>>(deg, rowptr, bsum);
    k_scan2<<<1, 256, 0, stream>>>(bsum, boff);
    k_scan3<<<NBLK, 256, 0, stream>>>(rowptr, boff, cursor);
    k_fill<<<(N_EDGES + 255) / 256, 256, 0, stream>>>(srcp, dstp, cursor, eidx);
    k_bounds<<<NBLK, 256, 0, stream>>>(batch, gstart);

    // ---- GCN layers ----
    const float* xcur = x;
    for (int l = 0; l < NL; ++l) {
        k_gemm<<<1024, 256, 0, stream>>>(xcur, convW + (size_t)l * FEA * FEA, dinv, H);
        k_gather<<<(N_NODES * 16 + 255) / 256, 256, 0, stream>>>(
            rowptr, eidx, dinv, H, convb + (size_t)l * FEA, X);
        xcur = X;
    }

    // ---- heads ----
    k_graph<<<NG * 4, 256, 0, stream>>>(X, gstart, nw, nb, out, psum_part);
    k_mlp<<<NG, 256, 0, stream>>>(psum_part, gstart, w1, b1, w2, b2, out + N_NODES);
}

// Round 6
// 286.825 us; speedup vs baseline: 16.4331x; 1.1549x over previous
//
#include <hip/hip_runtime.h>

#define N_NODES 50000
#define N_EDGES 800000
#define FEA 128
#define NL 3
#define AH 512
#define NG 64
#define NBLK 196   // ceil(50000/256)

typedef short bf16x8 __attribute__((ext_vector_type(8)));
typedef float f32x4 __attribute__((ext_vector_type(4)));

__device__ __forceinline__ ushort f2bf(float f) {   // RTN-even
    uint u = __float_as_uint(f);
    uint r = u + 0x7FFFu + ((u >> 16) & 1u);
    return (ushort)(r >> 16);
}
__device__ __forceinline__ float bf2f(ushort u) {
    return __uint_as_float((uint)u << 16);
}

// ---------------- degree histogram + per-edge rank ----------------
__global__ void k_deg(const int* __restrict__ dst, int* __restrict__ deg,
                      int* __restrict__ rank) {
    int i = blockIdx.x * blockDim.x + threadIdx.x;
    if (i < N_EDGES) rank[i] = atomicAdd(&deg[dst[i]], 1);
}

// ---------------- 3-kernel exclusive scan over PADDED degrees ----------------
__device__ __forceinline__ int block_scan_incl(int v, int* wsum) {
    int lane = threadIdx.x & 63, w = threadIdx.x >> 6;
    int s = v;
#pragma unroll
    for (int off = 1; off < 64; off <<= 1) {
        int t = __shfl_up(s, off);
        if (lane >= off) s += t;
    }
    if (lane == 63) wsum[w] = s;
    __syncthreads();
    int woff = 0;
    for (int k = 0; k < w; ++k) woff += wsum[k];
    return woff + s;  // block-wide inclusive
}

__global__ __launch_bounds__(256) void k_scan1(const int* __restrict__ deg,
                                               int* __restrict__ rowptr,
                                               int* __restrict__ bsum,
                                               float* __restrict__ dinv) {
    __shared__ int wsum[4];
    int i = blockIdx.x * 256 + threadIdx.x;
    int v = (i < N_NODES) ? deg[i] : 0;
    int pv = (v + 7) & ~7;                       // pad to multiple of 8
    int incl = block_scan_incl(pv, wsum);
    if (i < N_NODES) {
        rowptr[i] = incl - pv;                   // local exclusive
        dinv[i] = rsqrtf((float)v + 1.0f);
    }
    if (threadIdx.x == 255) bsum[blockIdx.x] = incl;
}

__global__ __launch_bounds__(256) void k_scan2(int* __restrict__ bsum,
                                               int* __restrict__ boff,
                                               int* __restrict__ rowptr) {
    __shared__ int wsum[4];
    int v = (threadIdx.x < NBLK) ? bsum[threadIdx.x] : 0;
    int incl = block_scan_incl(v, wsum);
    if (threadIdx.x < NBLK) boff[threadIdx.x] = incl - v;
    if (threadIdx.x == NBLK - 1) rowptr[N_NODES] = incl;  // total padded edges
}

__global__ __launch_bounds__(256) void k_scan3(int* __restrict__ rowptr,
                                               const int* __restrict__ boff) {
    int i = blockIdx.x * 256 + threadIdx.x;
    if (i < N_NODES) rowptr[i] += boff[blockIdx.x];
}

// ---------------- CSR fill (no atomics) ----------------
__global__ void k_fill(const int* __restrict__ src, const int* __restrict__ dst,
                       const int* __restrict__ rowptr, const int* __restrict__ rank,
                       ushort* __restrict__ eidx) {
    int e = blockIdx.x * blockDim.x + threadIdx.x;
    if (e < N_EDGES) eidx[rowptr[dst[e]] + rank[e]] = (ushort)src[e];
}

// fill pad slots with the zero row index (N_NODES)
__global__ void k_padfill(const int* __restrict__ deg, const int* __restrict__ rowptr,
                          ushort* __restrict__ eidx) {
    int i = blockIdx.x * blockDim.x + threadIdx.x;
    if (i >= N_NODES) return;
    int d = deg[i], r = rowptr[i];
    int pd = (d + 7) & ~7;
    for (int k = d; k < pd; ++k) eidx[r + k] = (ushort)N_NODES;
}

// ---------------- graph boundaries from sorted batch ----------------
__global__ void k_bounds(const int* __restrict__ batch, int* __restrict__ gstart) {
    int i = blockIdx.x * blockDim.x + threadIdx.x;
    if (i >= N_NODES) return;
    int b = batch[i];
    int bp = (i == 0) ? -1 : batch[i - 1];
    for (int g = bp + 1; g <= b; ++g) gstart[g] = i;
    if (i == N_NODES - 1)
        for (int g = b + 1; g <= NG; ++g) gstart[g] = N_NODES;
}

// ---------------- MFMA GEMM: H'(bf16) = dinv * (X @ W) ----------------
// Split-bf16: acc = xh@wh + xh@wl + xl@wh (f32 MFMA acc).
__global__ __launch_bounds__(256) void k_gemm(const float* __restrict__ X,
                                              const float* __restrict__ W,
                                              const float* __restrict__ dinv,
                                              ushort* __restrict__ H) {
    const int wv = threadIdx.x >> 6;
    const int lane = threadIdx.x & 63;
    const int lr = lane & 15;
    const int lk = lane >> 4;

    bf16x8 bhi[2][4], blo[2][4];
#pragma unroll
    for (int ct = 0; ct < 2; ++ct) {
        int col = wv * 32 + ct * 16 + lr;
#pragma unroll
        for (int kf = 0; kf < 4; ++kf) {
            int k0 = kf * 32 + lk * 8;
#pragma unroll
            for (int j = 0; j < 8; ++j) {
                float w = W[(size_t)(k0 + j) * FEA + col];
                ushort h = f2bf(w);
                bhi[ct][kf][j] = (short)h;
                blo[ct][kf][j] = (short)f2bf(w - bf2f(h));
            }
        }
    }

    for (int rt = blockIdx.x; rt < N_NODES / 16; rt += gridDim.x) {
        int r0 = rt * 16;
        const float* xrow = X + (size_t)(r0 + lr) * FEA;
        bf16x8 ahi[4], alo[4];
#pragma unroll
        for (int kf = 0; kf < 4; ++kf) {
            int k0 = kf * 32 + lk * 8;
            float4 u0 = *(const float4*)(xrow + k0);
            float4 u1 = *(const float4*)(xrow + k0 + 4);
            float xs[8] = {u0.x, u0.y, u0.z, u0.w, u1.x, u1.y, u1.z, u1.w};
#pragma unroll
            for (int j = 0; j < 8; ++j) {
                ushort h = f2bf(xs[j]);
                ahi[kf][j] = (short)h;
                alo[kf][j] = (short)f2bf(xs[j] - bf2f(h));
            }
        }
        f32x4 acc0 = {0.f, 0.f, 0.f, 0.f};
        f32x4 acc1 = {0.f, 0.f, 0.f, 0.f};
#pragma unroll
        for (int kf = 0; kf < 4; ++kf) {
            acc0 = __builtin_amdgcn_mfma_f32_16x16x32_bf16(ahi[kf], bhi[0][kf], acc0, 0, 0, 0);
            acc0 = __builtin_amdgcn_mfma_f32_16x16x32_bf16(ahi[kf], blo[0][kf], acc0, 0, 0, 0);
            acc0 = __builtin_amdgcn_mfma_f32_16x16x32_bf16(alo[kf], bhi[0][kf], acc0, 0, 0, 0);
            acc1 = __builtin_amdgcn_mfma_f32_16x16x32_bf16(ahi[kf], bhi[1][kf], acc1, 0, 0, 0);
            acc1 = __builtin_amdgcn_mfma_f32_16x16x32_bf16(ahi[kf], blo[1][kf], acc1, 0, 0, 0);
            acc1 = __builtin_amdgcn_mfma_f32_16x16x32_bf16(alo[kf], bhi[1][kf], acc1, 0, 0, 0);
        }
#pragma unroll
        for (int reg = 0; reg < 4; ++reg) {
            int orow = r0 + lk * 4 + reg;
            float s = dinv[orow];
            H[(size_t)orow * FEA + wv * 32 + lr]      = f2bf(acc0[reg] * s);
            H[(size_t)orow * FEA + wv * 32 + 16 + lr] = f2bf(acc1[reg] * s);
        }
    }
}

// ---------------- gather: X[d] = relu(dinv[d]*(sum H'[s] + H'[d]) + b) ----------------
// 16 threads per node; thread = 8 features. Segments padded to 8 -> tail-free
// 8-deep unrolled loop, 8 independent 16B loads in flight.
__global__ __launch_bounds__(256) void k_gather(const int* __restrict__ rowptr,
                                                const ushort* __restrict__ eidx,
                                                const float* __restrict__ dinv,
                                                const ushort* __restrict__ H,
                                                const float* __restrict__ b,
                                                float* __restrict__ X) {
    int t = blockIdx.x * 256 + threadIdx.x;
    int node = t >> 4;
    int c8 = t & 15;
    if (node >= N_NODES) return;
    const uint4* H4 = (const uint4*)H;  // 16 x uint4 per row
    int r0 = rowptr[node], r1 = rowptr[node + 1];

    float a[8] = {0.f, 0.f, 0.f, 0.f, 0.f, 0.f, 0.f, 0.f};
#define ACC8(u)                                                              \
    do {                                                                     \
        a[0] += __uint_as_float((u).x << 16);                                \
        a[1] += __uint_as_float((u).x & 0xffff0000u);                        \
        a[2] += __uint_as_float((u).y << 16);                                \
        a[3] += __uint_as_float((u).y & 0xffff0000u);                        \
        a[4] += __uint_as_float((u).z << 16);                                \
        a[5] += __uint_as_float((u).z & 0xffff0000u);                        \
        a[6] += __uint_as_float((u).w << 16);                                \
        a[7] += __uint_as_float((u).w & 0xffff0000u);                        \
    } while (0)

    uint4 sv = H4[(size_t)node * 16 + c8];  // self term
    ACC8(sv);

    for (int j = r0; j < r1; j += 8) {
        int s0 = eidx[j + 0], s1 = eidx[j + 1];
        int s2 = eidx[j + 2], s3 = eidx[j + 3];
        int s4 = eidx[j + 4], s5 = eidx[j + 5];
        int s6 = eidx[j + 6], s7 = eidx[j + 7];
        uint4 h0 = H4[(size_t)s0 * 16 + c8];
        uint4 h1 = H4[(size_t)s1 * 16 + c8];
        uint4 h2 = H4[(size_t)s2 * 16 + c8];
        uint4 h3 = H4[(size_t)s3 * 16 + c8];
        uint4 h4 = H4[(size_t)s4 * 16 + c8];
        uint4 h5 = H4[(size_t)s5 * 16 + c8];
        uint4 h6 = H4[(size_t)s6 * 16 + c8];
        uint4 h7 = H4[(size_t)s7 * 16 + c8];
        ACC8(h0); ACC8(h1); ACC8(h2); ACC8(h3);
        ACC8(h4); ACC8(h5); ACC8(h6); ACC8(h7);
    }
#undef ACC8

    float di = dinv[node];
    const float4* b4 = (const float4*)b;
    float4 bb0 = b4[c8 * 2], bb1 = b4[c8 * 2 + 1];
    float4 o0, o1;
    o0.x = fmaxf(a[0] * di + bb0.x, 0.f);
    o0.y = fmaxf(a[1] * di + bb0.y, 0.f);
    o0.z = fmaxf(a[2] * di + bb0.z, 0.f);
    o0.w = fmaxf(a[3] * di + bb0.w, 0.f);
    o1.x = fmaxf(a[4] * di + bb1.x, 0.f);
    o1.y = fmaxf(a[5] * di + bb1.y, 0.f);
    o1.z = fmaxf(a[6] * di + bb1.z, 0.f);
    o1.w = fmaxf(a[7] * di + bb1.w, 0.f);
    ((float4*)X)[(size_t)node * 32 + c8 * 2 + 0] = o0;
    ((float4*)X)[(size_t)node * 32 + c8 * 2 + 1] = o1;
}

// ---------------- per-graph pooled sums + node head (no atomics) ----------------
__global__ __launch_bounds__(256) void k_graph(const float* __restrict__ X,
                                               const int* __restrict__ gstart,
                                               const float* __restrict__ nw,
                                               const float* __restrict__ nb,
                                               float* __restrict__ out_node,
                                               float* __restrict__ psum_part) {
    int g = blockIdx.x >> 2, p = blockIdx.x & 3;
    int s = gstart[g], e = gstart[g + 1];
    int len = e - s;
    int l4 = (len + 3) >> 2;
    int ps = s + p * l4, pe = min(ps + l4, e);
    int wave = threadIdx.x >> 6, lane = threadIdx.x & 63;
    float2 w = ((const float2*)nw)[lane];
    float nbv = nb[0];
    float2 acc = {0.f, 0.f};
    for (int node = ps + wave; node < pe; node += 4) {
        float2 v = ((const float2*)(X + (size_t)node * FEA))[lane];
        acc.x += v.x; acc.y += v.y;
        float dot = v.x * w.x + v.y * w.y;
#pragma unroll
        for (int off = 32; off; off >>= 1) dot += __shfl_down(dot, off);
        if (lane == 0) out_node[node] = dot + nbv;
    }
    __shared__ float lds[4 * FEA];
    lds[wave * FEA + lane * 2 + 0] = acc.x;
    lds[wave * FEA + lane * 2 + 1] = acc.y;
    __syncthreads();
    if (threadIdx.x < FEA) {
        float sum = lds[threadIdx.x] + lds[FEA + threadIdx.x] +
                    lds[2 * FEA + threadIdx.x] + lds[3 * FEA + threadIdx.x];
        psum_part[(size_t)blockIdx.x * FEA + threadIdx.x] = sum;
    }
}

// ---------------- final MLP per graph ----------------
__global__ __launch_bounds__(256) void k_mlp(const float* __restrict__ psum_part,
                                             const int* __restrict__ gstart,
                                             const float* __restrict__ w1,
                                             const float* __restrict__ b1,
                                             const float* __restrict__ w2,
                                             const float* __restrict__ b2,
                                             float* __restrict__ out) {
    __shared__ float fea[FEA];
    __shared__ float h1[AH];
    int g = blockIdx.x;
    float cnt = fmaxf((float)(gstart[g + 1] - gstart[g]), 1.0f);
    if (threadIdx.x < FEA) {
        const float* pp = psum_part + (size_t)g * 4 * FEA + threadIdx.x;
        fea[threadIdx.x] = (pp[0] + pp[FEA] + pp[2 * FEA] + pp[3 * FEA]) / cnt;
    }
    __syncthreads();
    for (int j = threadIdx.x; j < AH; j += 256) {
        float acc = b1[j];
#pragma unroll 8
        for (int k = 0; k < FEA; ++k) acc += fea[k] * w1[k * AH + j];
        h1[j] = fmaxf(acc, 0.f);
    }
    __syncthreads();
    if (threadIdx.x < FEA) {
        int f = threadIdx.x;
        float acc = b2[f];
#pragma unroll 8
        for (int k = 0; k < AH; ++k) acc += h1[k] * w2[k * FEA + f];
        out[g * FEA + f] = acc;
    }
}

extern "C" void kernel_launch(void* const* d_in, const int* in_sizes, int n_in,
                              void* d_out, int out_size, void* d_ws, size_t ws_size,
                              hipStream_t stream) {
    const float* x     = (const float*)d_in[0];
    const int*   ei    = (const int*)d_in[1];
    const int*   batch = (const int*)d_in[2];
    const float* convW = (const float*)d_in[3];
    const float* convb = (const float*)d_in[4];
    const float* w1    = (const float*)d_in[5];
    const float* b1    = (const float*)d_in[6];
    const float* w2    = (const float*)d_in[7];
    const float* b2    = (const float*)d_in[8];
    const float* nw    = (const float*)d_in[9];
    const float* nb    = (const float*)d_in[10];
    float* out = (float*)d_out;

    // workspace layout (4-byte word offsets)
    char* wsb = (char*)d_ws;
    int*    deg    = (int*)wsb;                        // 50000
    float*  dinv   = (float*)(wsb + 50048ll * 4);      // 50000
    int*    rowptr = (int*)(wsb + 100096ll * 4);       // 50001
    int*    bsum   = (int*)(wsb + 150144ll * 4);       // 196
    int*    boff   = (int*)(wsb + 150344ll * 4);       // 196
    int*    gstart = (int*)(wsb + 150544ll * 4);       // 65
    int*    rank   = (int*)(wsb + 150656ll * 4);       // 800000
    ushort* eidx   = (ushort*)(wsb + 950656ll * 4);    // <=1.3M ushort
    ushort* H      = (ushort*)(wsb + 1600672ll * 4);   // (50001)*128 bf16
    float*  X      = (float*)(wsb + 4800736ll * 4);    // 6.4M f32
    float*  psum_part = (float*)(wsb + 11200736ll * 4);// 256*128

    const int* srcp = ei;
    const int* dstp = ei + N_EDGES;

    // ---- CSR build + boundaries (once per call) ----
    hipMemsetAsync(deg, 0, N_NODES * sizeof(int), stream);
    hipMemsetAsync(H + (size_t)N_NODES * FEA, 0, FEA * sizeof(ushort), stream); // zero pad row
    k_deg<<<(N_EDGES + 255) / 256, 256, 0, stream>>>(dstp, deg, rank);
    k_scan1<<<NBLK, 256, 0, stream>>>(deg, rowptr, bsum, dinv);
    k_scan2<<<1, 256, 0, stream>>>(bsum, boff, rowptr);
    k_scan3<<<NBLK, 256, 0, stream>>>(rowptr, boff);
    k_fill<<<(N_EDGES + 255) / 256, 256, 0, stream>>>(srcp, dstp, rowptr, rank, eidx);
    k_padfill<<<NBLK, 256, 0, stream>>>(deg, rowptr, eidx);
    k_bounds<<<NBLK, 256, 0, stream>>>(batch, gstart);

    // ---- GCN layers ----
    const float* xcur = x;
    for (int l = 0; l < NL; ++l) {
        k_gemm<<<1024, 256, 0, stream>>>(xcur, convW + (size_t)l * FEA * FEA, dinv, H);
        k_gather<<<(N_NODES * 16 + 255) / 256, 256, 0, stream>>>(
            rowptr, eidx, dinv, H, convb + (size_t)l * FEA, X);
        xcur = X;
    }

    // ---- heads ----
    k_graph<<<NG * 4, 256, 0, stream>>>(X, gstart, nw, nb, out, psum_part);
    k_mlp<<<NG, 256, 0, stream>>>(psum_part, gstart, w1, b1, w2, b2, out + N_NODES);
}

// Round 7
// 279.350 us; speedup vs baseline: 16.8729x; 1.0268x over previous
//
#include <hip/hip_runtime.h>

#define N_NODES 50000
#define N_EDGES 800000
#define FEA 128
#define NL 3
#define AH 512
#define NG 64
#define NBLK 196   // ceil(50000/256)

typedef short bf16x8 __attribute__((ext_vector_type(8)));
typedef float f32x4 __attribute__((ext_vector_type(4)));

__device__ __forceinline__ ushort f2bf(float f) {   // RTN-even
    uint u = __float_as_uint(f);
    uint r = u + 0x7FFFu + ((u >> 16) & 1u);
    return (ushort)(r >> 16);
}
__device__ __forceinline__ float bf2f(ushort u) {
    return __uint_as_float((uint)u << 16);
}

// ---------------- degree histogram + per-edge rank ----------------
__global__ void k_deg(const int* __restrict__ dst, int* __restrict__ deg,
                      int* __restrict__ rank) {
    int i = blockIdx.x * blockDim.x + threadIdx.x;
    if (i < N_EDGES) rank[i] = atomicAdd(&deg[dst[i]], 1);
}

// ---------------- 3-kernel exclusive scan over PADDED degrees ----------------
__device__ __forceinline__ int block_scan_incl(int v, int* wsum) {
    int lane = threadIdx.x & 63, w = threadIdx.x >> 6;
    int s = v;
#pragma unroll
    for (int off = 1; off < 64; off <<= 1) {
        int t = __shfl_up(s, off);
        if (lane >= off) s += t;
    }
    if (lane == 63) wsum[w] = s;
    __syncthreads();
    int woff = 0;
    for (int k = 0; k < w; ++k) woff += wsum[k];
    return woff + s;  // block-wide inclusive
}

__global__ __launch_bounds__(256) void k_scan1(const int* __restrict__ deg,
                                               int* __restrict__ rowptr,
                                               int* __restrict__ bsum,
                                               float* __restrict__ dinv) {
    __shared__ int wsum[4];
    int i = blockIdx.x * 256 + threadIdx.x;
    int v = (i < N_NODES) ? deg[i] : 0;
    int pv = (v + 7) & ~7;                       // pad to multiple of 8
    int incl = block_scan_incl(pv, wsum);
    if (i < N_NODES) {
        rowptr[i] = incl - pv;                   // local exclusive
        dinv[i] = rsqrtf((float)v + 1.0f);
    }
    if (threadIdx.x == 255) bsum[blockIdx.x] = incl;
}

__global__ __launch_bounds__(256) void k_scan2(int* __restrict__ bsum,
                                               int* __restrict__ boff,
                                               int* __restrict__ rowptr) {
    __shared__ int wsum[4];
    int v = (threadIdx.x < NBLK) ? bsum[threadIdx.x] : 0;
    int incl = block_scan_incl(v, wsum);
    if (threadIdx.x < NBLK) boff[threadIdx.x] = incl - v;
    if (threadIdx.x == NBLK - 1) rowptr[N_NODES] = incl;  // total padded edges
}

__global__ __launch_bounds__(256) void k_scan3(int* __restrict__ rowptr,
                                               const int* __restrict__ boff) {
    int i = blockIdx.x * 256 + threadIdx.x;
    if (i < N_NODES) rowptr[i] += boff[blockIdx.x];
}

// ---------------- CSR fill (no atomics) ----------------
__global__ void k_fill(const int* __restrict__ src, const int* __restrict__ dst,
                       const int* __restrict__ rowptr, const int* __restrict__ rank,
                       ushort* __restrict__ eidx) {
    int e = blockIdx.x * blockDim.x + threadIdx.x;
    if (e < N_EDGES) eidx[rowptr[dst[e]] + rank[e]] = (ushort)src[e];
}

// fill pad slots with the zero row index (N_NODES)
__global__ void k_padfill(const int* __restrict__ deg, const int* __restrict__ rowptr,
                          ushort* __restrict__ eidx) {
    int i = blockIdx.x * blockDim.x + threadIdx.x;
    if (i >= N_NODES) return;
    int d = deg[i], r = rowptr[i];
    int pd = (d + 7) & ~7;
    for (int k = d; k < pd; ++k) eidx[r + k] = (ushort)N_NODES;
}

// ---------------- graph boundaries from sorted batch ----------------
__global__ void k_bounds(const int* __restrict__ batch, int* __restrict__ gstart) {
    int i = blockIdx.x * blockDim.x + threadIdx.x;
    if (i >= N_NODES) return;
    int b = batch[i];
    int bp = (i == 0) ? -1 : batch[i - 1];
    for (int g = bp + 1; g <= b; ++g) gstart[g] = i;
    if (i == N_NODES - 1)
        for (int g = b + 1; g <= NG; ++g) gstart[g] = N_NODES;
}

// ---------------- weight transposes for the head MLP ----------------
__global__ __launch_bounds__(256) void k_tr(const float* __restrict__ w1,
                                            const float* __restrict__ w2,
                                            float* __restrict__ w1T,
                                            float* __restrict__ w2T) {
    int idx = blockIdx.x * 256 + threadIdx.x;   // 0..131071
    if (idx < FEA * AH) {
        int k = idx >> 9, j = idx & 511;        // w1[k][j]
        w1T[(size_t)j * FEA + k] = w1[idx];
    } else {
        int t = idx - FEA * AH;
        int k = t >> 7, f = t & 127;            // w2[k][f]
        w2T[(size_t)f * AH + k] = w2[t];
    }
}

// ---------------- MFMA GEMM: H'(bf16) = dinv * (X @ W) ----------------
// Split-bf16: acc = xh@wh + xh@wl + xl@wh (f32 MFMA acc).
__global__ __launch_bounds__(256) void k_gemm(const float* __restrict__ X,
                                              const float* __restrict__ W,
                                              const float* __restrict__ dinv,
                                              ushort* __restrict__ H) {
    const int wv = threadIdx.x >> 6;
    const int lane = threadIdx.x & 63;
    const int lr = lane & 15;
    const int lk = lane >> 4;

    bf16x8 bhi[2][4], blo[2][4];
#pragma unroll
    for (int ct = 0; ct < 2; ++ct) {
        int col = wv * 32 + ct * 16 + lr;
#pragma unroll
        for (int kf = 0; kf < 4; ++kf) {
            int k0 = kf * 32 + lk * 8;
#pragma unroll
            for (int j = 0; j < 8; ++j) {
                float w = W[(size_t)(k0 + j) * FEA + col];
                ushort h = f2bf(w);
                bhi[ct][kf][j] = (short)h;
                blo[ct][kf][j] = (short)f2bf(w - bf2f(h));
            }
        }
    }

    for (int rt = blockIdx.x; rt < N_NODES / 16; rt += gridDim.x) {
        int r0 = rt * 16;
        const float* xrow = X + (size_t)(r0 + lr) * FEA;
        bf16x8 ahi[4], alo[4];
#pragma unroll
        for (int kf = 0; kf < 4; ++kf) {
            int k0 = kf * 32 + lk * 8;
            float4 u0 = *(const float4*)(xrow + k0);
            float4 u1 = *(const float4*)(xrow + k0 + 4);
            float xs[8] = {u0.x, u0.y, u0.z, u0.w, u1.x, u1.y, u1.z, u1.w};
#pragma unroll
            for (int j = 0; j < 8; ++j) {
                ushort h = f2bf(xs[j]);
                ahi[kf][j] = (short)h;
                alo[kf][j] = (short)f2bf(xs[j] - bf2f(h));
            }
        }
        f32x4 acc0 = {0.f, 0.f, 0.f, 0.f};
        f32x4 acc1 = {0.f, 0.f, 0.f, 0.f};
#pragma unroll
        for (int kf = 0; kf < 4; ++kf) {
            acc0 = __builtin_amdgcn_mfma_f32_16x16x32_bf16(ahi[kf], bhi[0][kf], acc0, 0, 0, 0);
            acc0 = __builtin_amdgcn_mfma_f32_16x16x32_bf16(ahi[kf], blo[0][kf], acc0, 0, 0, 0);
            acc0 = __builtin_amdgcn_mfma_f32_16x16x32_bf16(alo[kf], bhi[0][kf], acc0, 0, 0, 0);
            acc1 = __builtin_amdgcn_mfma_f32_16x16x32_bf16(ahi[kf], bhi[1][kf], acc1, 0, 0, 0);
            acc1 = __builtin_amdgcn_mfma_f32_16x16x32_bf16(ahi[kf], blo[1][kf], acc1, 0, 0, 0);
            acc1 = __builtin_amdgcn_mfma_f32_16x16x32_bf16(alo[kf], bhi[1][kf], acc1, 0, 0, 0);
        }
#pragma unroll
        for (int reg = 0; reg < 4; ++reg) {
            int orow = r0 + lk * 4 + reg;
            float s = dinv[orow];
            H[(size_t)orow * FEA + wv * 32 + lr]      = f2bf(acc0[reg] * s);
            H[(size_t)orow * FEA + wv * 32 + 16 + lr] = f2bf(acc1[reg] * s);
        }
    }
}

// ---------------- gather: X[d] = relu(dinv[d]*(sum H'[s] + H'[d]) + b) ----------------
__global__ __launch_bounds__(256) void k_gather(const int* __restrict__ rowptr,
                                                const ushort* __restrict__ eidx,
                                                const float* __restrict__ dinv,
                                                const ushort* __restrict__ H,
                                                const float* __restrict__ b,
                                                float* __restrict__ X) {
    int t = blockIdx.x * 256 + threadIdx.x;
    int node = t >> 4;
    int c8 = t & 15;
    if (node >= N_NODES) return;
    const uint4* H4 = (const uint4*)H;  // 16 x uint4 per row
    int r0 = rowptr[node], r1 = rowptr[node + 1];

    float a[8] = {0.f, 0.f, 0.f, 0.f, 0.f, 0.f, 0.f, 0.f};
#define ACC8(u)                                                              \
    do {                                                                     \
        a[0] += __uint_as_float((u).x << 16);                                \
        a[1] += __uint_as_float((u).x & 0xffff0000u);                        \
        a[2] += __uint_as_float((u).y << 16);                                \
        a[3] += __uint_as_float((u).y & 0xffff0000u);                        \
        a[4] += __uint_as_float((u).z << 16);                                \
        a[5] += __uint_as_float((u).z & 0xffff0000u);                        \
        a[6] += __uint_as_float((u).w << 16);                                \
        a[7] += __uint_as_float((u).w & 0xffff0000u);                        \
    } while (0)

    uint4 sv = H4[(size_t)node * 16 + c8];  // self term
    ACC8(sv);

    for (int j = r0; j < r1; j += 8) {
        int s0 = eidx[j + 0], s1 = eidx[j + 1];
        int s2 = eidx[j + 2], s3 = eidx[j + 3];
        int s4 = eidx[j + 4], s5 = eidx[j + 5];
        int s6 = eidx[j + 6], s7 = eidx[j + 7];
        uint4 h0 = H4[(size_t)s0 * 16 + c8];
        uint4 h1 = H4[(size_t)s1 * 16 + c8];
        uint4 h2 = H4[(size_t)s2 * 16 + c8];
        uint4 h3 = H4[(size_t)s3 * 16 + c8];
        uint4 h4 = H4[(size_t)s4 * 16 + c8];
        uint4 h5 = H4[(size_t)s5 * 16 + c8];
        uint4 h6 = H4[(size_t)s6 * 16 + c8];
        uint4 h7 = H4[(size_t)s7 * 16 + c8];
        ACC8(h0); ACC8(h1); ACC8(h2); ACC8(h3);
        ACC8(h4); ACC8(h5); ACC8(h6); ACC8(h7);
    }
#undef ACC8

    float di = dinv[node];
    const float4* b4 = (const float4*)b;
    float4 bb0 = b4[c8 * 2], bb1 = b4[c8 * 2 + 1];
    float4 o0, o1;
    o0.x = fmaxf(a[0] * di + bb0.x, 0.f);
    o0.y = fmaxf(a[1] * di + bb0.y, 0.f);
    o0.z = fmaxf(a[2] * di + bb0.z, 0.f);
    o0.w = fmaxf(a[3] * di + bb0.w, 0.f);
    o1.x = fmaxf(a[4] * di + bb1.x, 0.f);
    o1.y = fmaxf(a[5] * di + bb1.y, 0.f);
    o1.z = fmaxf(a[6] * di + bb1.z, 0.f);
    o1.w = fmaxf(a[7] * di + bb1.w, 0.f);
    ((float4*)X)[(size_t)node * 32 + c8 * 2 + 0] = o0;
    ((float4*)X)[(size_t)node * 32 + c8 * 2 + 1] = o1;
}

// ---------------- per-graph pooled sums + node head (no atomics) ----------------
__global__ __launch_bounds__(256) void k_graph(const float* __restrict__ X,
                                               const int* __restrict__ gstart,
                                               const float* __restrict__ nw,
                                               const float* __restrict__ nb,
                                               float* __restrict__ out_node,
                                               float* __restrict__ psum_part) {
    int g = blockIdx.x >> 2, p = blockIdx.x & 3;
    int s = gstart[g], e = gstart[g + 1];
    int len = e - s;
    int l4 = (len + 3) >> 2;
    int ps = s + p * l4, pe = min(ps + l4, e);
    int wave = threadIdx.x >> 6, lane = threadIdx.x & 63;
    float2 w = ((const float2*)nw)[lane];
    float nbv = nb[0];
    float2 acc = {0.f, 0.f};
    for (int node = ps + wave; node < pe; node += 4) {
        float2 v = ((const float2*)(X + (size_t)node * FEA))[lane];
        acc.x += v.x; acc.y += v.y;
        float dot = v.x * w.x + v.y * w.y;
#pragma unroll
        for (int off = 32; off; off >>= 1) dot += __shfl_down(dot, off);
        if (lane == 0) out_node[node] = dot + nbv;
    }
    __shared__ float lds[4 * FEA];
    lds[wave * FEA + lane * 2 + 0] = acc.x;
    lds[wave * FEA + lane * 2 + 1] = acc.y;
    __syncthreads();
    if (threadIdx.x < FEA) {
        float sum = lds[threadIdx.x] + lds[FEA + threadIdx.x] +
                    lds[2 * FEA + threadIdx.x] + lds[3 * FEA + threadIdx.x];
        psum_part[(size_t)blockIdx.x * FEA + threadIdx.x] = sum;
    }
}

// ---------------- MLP layer 1: h1[g][j] = relu(fea[g] . w1T[j] + b1[j]) ----------------
// 128 blocks x 256 thr; block covers 4 j-cols x 64 graphs; fea staged in LDS.
__global__ __launch_bounds__(256) void k_mlp1(const float* __restrict__ psum_part,
                                              const int* __restrict__ gstart,
                                              const float* __restrict__ w1T,
                                              const float* __restrict__ b1,
                                              float* __restrict__ h1ws) {
    __shared__ float feas[NG * 132];   // pad 132 to spread banks
    for (int idx = threadIdx.x; idx < NG * FEA; idx += 256) {
        int g = idx >> 7, f = idx & 127;
        const float* pp = psum_part + (size_t)g * 4 * FEA + f;
        float cnt = fmaxf((float)(gstart[g + 1] - gstart[g]), 1.0f);
        feas[g * 132 + f] = (pp[0] + pp[FEA] + pp[2 * FEA] + pp[3 * FEA]) / cnt;
    }
    __syncthreads();
    int g = threadIdx.x >> 2, jj = threadIdx.x & 3;
    int j = blockIdx.x * 4 + jj;
    const float4* fr = (const float4*)(feas + g * 132);
    const float4* wr = (const float4*)(w1T + (size_t)j * FEA);
    float4 a0 = {0.f, 0.f, 0.f, 0.f}, a1 = {0.f, 0.f, 0.f, 0.f};
#pragma unroll
    for (int i = 0; i < 16; ++i) {
        float4 f0 = fr[2 * i], w0 = wr[2 * i];
        float4 f1 = fr[2 * i + 1], w1v = wr[2 * i + 1];
        a0.x += f0.x * w0.x; a0.y += f0.y * w0.y;
        a0.z += f0.z * w0.z; a0.w += f0.w * w0.w;
        a1.x += f1.x * w1v.x; a1.y += f1.y * w1v.y;
        a1.z += f1.z * w1v.z; a1.w += f1.w * w1v.w;
    }
    float s = (a0.x + a0.y) + (a0.z + a0.w) + (a1.x + a1.y) + (a1.z + a1.w);
    h1ws[(size_t)g * AH + j] = fmaxf(s + b1[j], 0.f);
}

// ---------------- MLP layer 2: out[g][f] = h1[g] . w2T[f] + b2[f] ----------------
// 128 blocks (one f each) x 256 thr; 4 threads split K=512 per graph.
__global__ __launch_bounds__(256) void k_mlp2(const float* __restrict__ h1ws,
                                              const float* __restrict__ w2T,
                                              const float* __restrict__ b2,
                                              float* __restrict__ out_fea) {
    int f = blockIdx.x;
    int g = threadIdx.x >> 2, q = threadIdx.x & 3;
    const float4* hr = (const float4*)(h1ws + (size_t)g * AH + q * 128);
    const float4* wr = (const float4*)(w2T + (size_t)f * AH + q * 128);
    float4 a0 = {0.f, 0.f, 0.f, 0.f}, a1 = {0.f, 0.f, 0.f, 0.f};
#pragma unroll
    for (int i = 0; i < 16; ++i) {
        float4 h0 = hr[2 * i], w0 = wr[2 * i];
        float4 h1 = hr[2 * i + 1], w1v = wr[2 * i + 1];
        a0.x += h0.x * w0.x; a0.y += h0.y * w0.y;
        a0.z += h0.z * w0.z; a0.w += h0.w * w0.w;
        a1.x += h1.x * w1v.x; a1.y += h1.y * w1v.y;
        a1.z += h1.z * w1v.z; a1.w += h1.w * w1v.w;
    }
    float p = (a0.x + a0.y) + (a0.z + a0.w) + (a1.x + a1.y) + (a1.z + a1.w);
    p += __shfl_xor(p, 1);
    p += __shfl_xor(p, 2);
    if (q == 0) out_fea[(size_t)g * FEA + f] = p + b2[f];
}

extern "C" void kernel_launch(void* const* d_in, const int* in_sizes, int n_in,
                              void* d_out, int out_size, void* d_ws, size_t ws_size,
                              hipStream_t stream) {
    const float* x     = (const float*)d_in[0];
    const int*   ei    = (const int*)d_in[1];
    const int*   batch = (const int*)d_in[2];
    const float* convW = (const float*)d_in[3];
    const float* convb = (const float*)d_in[4];
    const float* w1    = (const float*)d_in[5];
    const float* b1    = (const float*)d_in[6];
    const float* w2    = (const float*)d_in[7];
    const float* b2    = (const float*)d_in[8];
    const float* nw    = (const float*)d_in[9];
    const float* nb    = (const float*)d_in[10];
    float* out = (float*)d_out;

    // workspace layout (4-byte word offsets)
    char* wsb = (char*)d_ws;
    int*    deg    = (int*)wsb;                        // 50000
    float*  dinv   = (float*)(wsb + 50048ll * 4);      // 50000
    int*    rowptr = (int*)(wsb + 100096ll * 4);       // 50001
    int*    bsum   = (int*)(wsb + 150144ll * 4);       // 196
    int*    boff   = (int*)(wsb + 150344ll * 4);       // 196
    int*    gstart = (int*)(wsb + 150544ll * 4);       // 65
    int*    rank   = (int*)(wsb + 150656ll * 4);       // 800000 (reused below)
    // rank area reuse after k_fill: w1T | w2T | h1ws  (131072+32768 < 800000)
    float*  w1T    = (float*)rank;                     // 65536
    float*  w2T    = (float*)(rank + 65536);           // 65536
    float*  h1ws   = (float*)(rank + 131072);          // 32768
    ushort* eidx   = (ushort*)(wsb + 950656ll * 4);    // <=1.3M ushort
    ushort* H      = (ushort*)(wsb + 1600672ll * 4);   // (50001)*128 bf16
    float*  X      = (float*)(wsb + 4800736ll * 4);    // 6.4M f32
    float*  psum_part = (float*)(wsb + 11200736ll * 4);// 256*128

    const int* srcp = ei;
    const int* dstp = ei + N_EDGES;

    // ---- CSR build + boundaries (once per call) ----
    hipMemsetAsync(deg, 0, N_NODES * sizeof(int), stream);
    hipMemsetAsync(H + (size_t)N_NODES * FEA, 0, FEA * sizeof(ushort), stream); // zero pad row
    k_deg<<<(N_EDGES + 255) / 256, 256, 0, stream>>>(dstp, deg, rank);
    k_scan1<<<NBLK, 256, 0, stream>>>(deg, rowptr, bsum, dinv);
    k_scan2<<<1, 256, 0, stream>>>(bsum, boff, rowptr);
    k_scan3<<<NBLK, 256, 0, stream>>>(rowptr, boff);
    k_fill<<<(N_EDGES + 255) / 256, 256, 0, stream>>>(srcp, dstp, rowptr, rank, eidx);
    k_padfill<<<NBLK, 256, 0, stream>>>(deg, rowptr, eidx);
    k_bounds<<<NBLK, 256, 0, stream>>>(batch, gstart);
    k_tr<<<512, 256, 0, stream>>>(w1, w2, w1T, w2T);   // after k_fill (rank reuse)

    // ---- GCN layers ----
    const float* xcur = x;
    for (int l = 0; l < NL; ++l) {
        k_gemm<<<1024, 256, 0, stream>>>(xcur, convW + (size_t)l * FEA * FEA, dinv, H);
        k_gather<<<(N_NODES * 16 + 255) / 256, 256, 0, stream>>>(
            rowptr, eidx, dinv, H, convb + (size_t)l * FEA, X);
        xcur = X;
    }

    // ---- heads ----
    k_graph<<<NG * 4, 256, 0, stream>>>(X, gstart, nw, nb, out, psum_part);
    k_mlp1<<<128, 256, 0, stream>>>(psum_part, gstart, w1T, b1, h1ws);
    k_mlp2<<<128, 256, 0, stream>>>(h1ws, w2T, b2, out + N_NODES);
}